// Round 13
// baseline (248.857 us; speedup 1.0000x reference)
//
#include <hip/hip_runtime.h>
#include <math.h>

// S4D — round 19: r18 pipeline, conv bank-conflict fix.
//  - dApow table transposed to [n][66] (pad 66): kills the 64-way LDS
//    conflicts in k-build (was stride-32 = single-bank for all 64 lanes)
//    and V-build (same), ~6K conflict-cycles/block of the measured 9.67K.
//  - P7 reuses P5's Xl fragment registers (8 x f16x8 kept live through the
//    P6 recurrence): 8 fewer ds_read_b128 per wave. VGPR ~120 < 128.
//  - A/C transposes: f16 side widened to f16x8 (half the VMEM instrs);
//    expected ~null (r17==r18 proved BW-bound) but free.

#define H_  512
#define L_  4096
#define B_  8
#define N2_ 32
#define NC  64            // chunks of 64 timesteps
#define THREADS 256
#define COLS 256          // columns per conv block = 4 b x 64 c
#define RSTR 72           // padded LDS row stride, f16 units

typedef _Float16 f16;
typedef _Float16 f16x8 __attribute__((ext_vector_type(8)));
typedef _Float16 f16x4 __attribute__((ext_vector_type(4)));
typedef float    f32x4 __attribute__((ext_vector_type(4)));

__device__ __forceinline__ float bfly1(float v) {   // xor 1: quad_perm [1,0,3,2]
    return __int_as_float(__builtin_amdgcn_update_dpp(
        0, __float_as_int(v), 0xB1, 0xf, 0xf, true));
}

// ---------------- kernel A: x (B,L,H) f32 -> xT (H,B,L) f16 ----------------
__global__ __launch_bounds__(256) void k_trin(
    const float* __restrict__ x, f16* __restrict__ xT)
{
    __shared__ float tl[64][65];
    const int bid = (int)blockIdx.x;
    const int tt = bid & 63, hh = (bid >> 6) & 7, b = bid >> 9;
    const int t0 = tt * 64, h0 = hh * 64;
    const int tid = threadIdx.x;

    const float* src = x + ((size_t)b * L_ + t0) * H_ + h0;
#pragma unroll
    for (int i = 0; i < 4; ++i) {
        const int e = i * 256 + tid;
        const int t = e >> 4, hq = e & 15;          // load 4 consecutive h
        const f32x4 v = *(const f32x4*)&src[(size_t)t * H_ + hq * 4];
#pragma unroll
        for (int j = 0; j < 4; ++j) tl[hq * 4 + j][t] = v[j];
    }
    __syncthreads();
#pragma unroll
    for (int i = 0; i < 2; ++i) {
        const int e = i * 256 + tid;
        const int hI = e >> 3, tq = e & 7;          // store 8 consecutive t
        f16x8 pk;
#pragma unroll
        for (int j = 0; j < 8; ++j) pk[j] = (f16)tl[hI][tq * 8 + j];
        *(f16x8*)&xT[((size_t)(h0 + hI) * B_ + b) * L_ + t0 + tq * 8] = pk;
    }
}

// ---------------- kernel C: yT (H,B,L) f16 -> y (B,L,H) f32 ----------------
__global__ __launch_bounds__(256) void k_trout(
    const f16* __restrict__ yT, float* __restrict__ y)
{
    __shared__ float tl[64][65];
    const int bid = (int)blockIdx.x;
    const int tt = bid & 63, hh = (bid >> 6) & 7, b = bid >> 9;
    const int t0 = tt * 64, h0 = hh * 64;
    const int tid = threadIdx.x;

#pragma unroll
    for (int i = 0; i < 2; ++i) {
        const int e = i * 256 + tid;
        const int hI = e >> 3, tq = e & 7;          // load 8 consecutive t
        const f16x8 v = *(const f16x8*)
            &yT[((size_t)(h0 + hI) * B_ + b) * L_ + t0 + tq * 8];
#pragma unroll
        for (int j = 0; j < 8; ++j) tl[tq * 8 + j][hI] = (float)v[j];
    }
    __syncthreads();
    float* dst = y + ((size_t)b * L_ + t0) * H_ + h0;
#pragma unroll
    for (int i = 0; i < 4; ++i) {
        const int e = i * 256 + tid;
        const int t = e >> 4, hq = e & 15;          // store 4 consecutive h
        f32x4 v;
#pragma unroll
        for (int j = 0; j < 4; ++j) v[j] = tl[t][hq * 4 + j];
        *(f32x4*)&dst[(size_t)t * H_ + hq * 4] = v;
    }
}

// ---------------- kernel B: per-h chunked convolution ----------------------
__global__ __launch_bounds__(THREADS, 2) void s4d_conv_kernel(
    const f16*  __restrict__ xT,          // (H, B, L) f16
    const float* __restrict__ log_dt,     // (H,)
    const float* __restrict__ A_real_log, // (H, N2)
    const float* __restrict__ A_imag,     // (H, N2)
    const float* __restrict__ B_re,       // (H, N2)
    const float* __restrict__ B_im,       // (H, N2)
    const float* __restrict__ C_re,       // (H, N2)
    const float* __restrict__ C_im,       // (H, N2)
    const float* __restrict__ Dv,         // (H,)
    f16*  __restrict__ yT,                // (H, B, L) f16 (gelu'd)
    float* __restrict__ st_re,            // (B, H, N2)
    float* __restrict__ st_im)            // (B, H, N2)
{
    __shared__ f16 Xl[COLS][RSTR];                 // 36.9 KB
    __shared__ f16 PU[COLS][RSTR];                 // 36.9 KB
    __shared__ float s_xr[32], s_xi[32], s_dBr[32], s_dBi[32],
                     s_wr[32], s_wi[32], s_wdr[32], s_wdi[32],
                     s_Lr[32], s_Li[32], s_k[64];

    // XCD swizzle: XCD k owns h in [k*64, (k+1)*64), both b-halves.
    const int bid = (int)blockIdx.x;
    const int li  = bid >> 3;                       // 0..127
    const int h   = (bid & 7) * 64 + (li >> 1);
    const int bh  = li & 1;                         // batch half (b = bh*4+w)

    const int tid = threadIdx.x;
    const int l   = tid & 63;
    const int w   = tid >> 6;                       // wave = local batch

    // ---- P0: per-mode ZOH constants (32 threads) ----
    if (tid < 32) {
        const int n = tid, hn = h * N2_ + n;
        const float dt = expf(log_dt[h]);
        const float Ar = -expf(A_real_log[hn]);
        const float Ai = A_imag[hn];
        const float xr = dt * Ar, xi = dt * Ai;
        s_xr[n] = xr; s_xi[n] = xi;
        const float ex = expf(xr), cs = cosf(xi), sn = sinf(xi);
        const float sh  = sinf(0.5f * xi);
        const float emr = expm1f(xr) * cs - 2.0f * sh * sh;  // Re(expm1(dtA))
        const float emi = ex * sn;
        const float ia  = 1.0f / (Ar * Ar + Ai * Ai);
        const float tr  = (emr * Ar + emi * Ai) * ia;
        const float ti  = (emi * Ar - emr * Ai) * ia;
        const float Brv = B_re[hn], Biv = B_im[hn];
        const float dBr = Brv * tr - Biv * ti, dBi = Brv * ti + Biv * tr;
        s_dBr[n] = dBr; s_dBi[n] = dBi;
        const float wr = 2.0f * C_re[hn], wi = 2.0f * C_im[hn];
        s_wr[n] = wr; s_wi[n] = wi;
        s_wdr[n] = wr * dBr - wi * dBi;             // w*dB
        s_wdi[n] = wr * dBi + wi * dBr;
    }
    const float Dh = Dv[h];
    __syncthreads();

    // ---- P1: dApow[n][p] = dA_n^p, p = 0..64, TRANSPOSED layout [n][66]
    // (stride 66: %32 = 2 -> all build-phase reads are conflict-free;
    //  the old [p][32] layout put column reads in ONE bank = 64-way) ----
    float* pr = (float*)&PU[0][0];                  // [32][66]
    float* pi = pr + 32 * 66;
    for (int e = tid; e < 2048; e += THREADS) {     // p = 0..63
        const int n = e >> 6, p = e & 63;
        const float ex = expf((float)p * s_xr[n]);
        float sn, cs; sincosf((float)p * s_xi[n], &sn, &cs);
        pr[n * 66 + p] = ex * cs; pi[n * 66 + p] = ex * sn;
    }
    if (tid < 32) {                                 // p = 64
        const int n = tid;
        const float ex = expf(64.f * s_xr[n]);
        float sn, cs; sincosf(64.f * s_xi[n], &sn, &cs);
        pr[n * 66 + 64] = ex * cs; pi[n * 66 + 64] = ex * sn;
    }
    __syncthreads();

    // ---- P2: build k, Lambda, M, V (then T after barrier) ----
    if (tid < 64) {                                 // k[d] = Re(w dB dA^d)
        float acc = 0.f;
        for (int n = 0; n < 32; ++n)
            acc += s_wdr[n] * pr[n * 66 + tid] - s_wdi[n] * pi[n * 66 + tid];
        s_k[tid] = acc;
    }
    if (tid < 32) { s_Lr[tid] = pr[tid * 66 + 64]; s_Li[tid] = pi[tid * 66 + 64]; }
    for (int e = tid; e < 4096; e += THREADS) {     // M[t][j], rows 64..127
        const int t = e >> 6, j = e & 63, n = j >> 1;
        const float re = pr[n * 66 + t + 1], im = pi[n * 66 + t + 1];
        const float mv = (j & 1) ? -(s_wr[n] * im + s_wi[n] * re)
                                 :  (s_wr[n] * re - s_wi[n] * im);
        Xl[64 + t][j] = (f16)mv;
    }
    for (int e = tid; e < 4096; e += THREADS) {     // V[r][s], rows 128..191
        const int r = e >> 6, s = e & 63, n = r >> 1;
        const float re = pr[n * 66 + 63 - s], im = pi[n * 66 + 63 - s];
        const float vv = (r & 1) ? (s_dBr[n] * im + s_dBi[n] * re)
                                 : (s_dBr[n] * re - s_dBi[n] * im);
        Xl[128 + r][s] = (f16)vv;
    }
    __syncthreads();
    for (int e = tid; e < 4096; e += THREADS) {     // T[t][s], rows 0..63
        const int t = e >> 6, s = e & 63;
        Xl[t][s] = (f16)((s <= t) ? s_k[t - s] : 0.f);
    }
    __syncthreads();

    // ---- P3: A-fragments to registers (row = l&15, kgroup = l>>4) ----
    const int row16 = l & 15, kg = l >> 4;
    f16x8 Tf[4][2], Mf[4][2], Vf[4][2];
#pragma unroll
    for (int mt = 0; mt < 4; ++mt)
#pragma unroll
        for (int ks = 0; ks < 2; ++ks) {
            const int off = ks * 32 + kg * 8;
            Tf[mt][ks] = *(const f16x8*)&Xl[      mt * 16 + row16][off];
            Mf[mt][ks] = *(const f16x8*)&Xl[ 64 + mt * 16 + row16][off];
            Vf[mt][ks] = *(const f16x8*)&Xl[128 + mt * 16 + row16][off];
        }
    __syncthreads();   // frags live in regs; Xl area free for X

    // ---- P4: load X — contiguous f16 reads from xT (thread = column) ----
    {
        const int col = tid, b = bh * 4 + (col >> 6), c = col & 63;
        const f16* xg = xT + ((size_t)h * B_ + b) * L_ + (size_t)c * 64;
#pragma unroll
        for (int s0 = 0; s0 < 64; s0 += 8)
            *(f16x8*)&Xl[col][s0] = *(const f16x8*)&xg[s0];
    }
    __syncthreads();

    const int colbase = w * 64;

    // ---- P5: P = V @ X; keep the X fragments live for P7 ----
    f16x8 xbA[4], xbB[4];
#pragma unroll 1
    for (int nt = 0; nt < 4; ++nt) {
        const int col = colbase + nt * 16 + row16;
        xbA[nt] = *(const f16x8*)&Xl[col][kg * 8];
        xbB[nt] = *(const f16x8*)&Xl[col][32 + kg * 8];
        f32x4 ac0 = {0.f,0.f,0.f,0.f}, ac1 = {0.f,0.f,0.f,0.f},
              ac2 = {0.f,0.f,0.f,0.f}, ac3 = {0.f,0.f,0.f,0.f};
        ac0 = __builtin_amdgcn_mfma_f32_16x16x32_f16(Vf[0][0], xbA[nt], ac0, 0,0,0);
        ac0 = __builtin_amdgcn_mfma_f32_16x16x32_f16(Vf[0][1], xbB[nt], ac0, 0,0,0);
        ac1 = __builtin_amdgcn_mfma_f32_16x16x32_f16(Vf[1][0], xbA[nt], ac1, 0,0,0);
        ac1 = __builtin_amdgcn_mfma_f32_16x16x32_f16(Vf[1][1], xbB[nt], ac1, 0,0,0);
        ac2 = __builtin_amdgcn_mfma_f32_16x16x32_f16(Vf[2][0], xbA[nt], ac2, 0,0,0);
        ac2 = __builtin_amdgcn_mfma_f32_16x16x32_f16(Vf[2][1], xbB[nt], ac2, 0,0,0);
        ac3 = __builtin_amdgcn_mfma_f32_16x16x32_f16(Vf[3][0], xbA[nt], ac3, 0,0,0);
        ac3 = __builtin_amdgcn_mfma_f32_16x16x32_f16(Vf[3][1], xbB[nt], ac3, 0,0,0);
        f32x4 a4[4] = {ac0, ac1, ac2, ac3};
#pragma unroll
        for (int mt = 0; mt < 4; ++mt) {
            f16x4 pv;
            pv[0] = (f16)a4[mt][0]; pv[1] = (f16)a4[mt][1];
            pv[2] = (f16)a4[mt][2]; pv[3] = (f16)a4[mt][3];
            *(f16x4*)&PU[col][mt * 16 + kg * 4] = pv;   // row j, col
        }
    }

    // ---- P6: wave-local diagonal recurrence over chunks (b = bh*4+w) ----
    {
        const int j = l, n = j >> 1;
        const float lr  = s_Lr[n];
        const float lis = (j & 1) ? s_Li[n] : -s_Li[n];
        float u = 0.f;
        for (int c = 0; c < NC; ++c) {
            const int col = colbase + c;
            const float pv = (float)PU[col][j];     // P_c component
            PU[col][j] = (f16)u;                    // store u_in(c) pre-update
            const float usw = bfly1(u);
            u = fmaf(lr, u, fmaf(lis, usw, pv));
        }
        const int pairIdx = (bh * 4 + w) * H_ + h;
        if ((j & 1) == 0) st_re[(size_t)pairIdx * N2_ + n] = u;
        else              st_im[(size_t)pairIdx * N2_ + n] = u;
    }

    // ---- P7: Y = T @ X + M @ U + D*x, gelu, contiguous f16 store to yT ----
    {
        const int b = bh * 4 + w;
        f16* yb = yT + ((size_t)h * B_ + b) * L_;
#pragma unroll 1
        for (int nt = 0; nt < 4; ++nt) {
            const int col = colbase + nt * 16 + row16;
            const int cc  = nt * 16 + row16;        // chunk index
            const f16x8 ub0 = *(const f16x8*)&PU[col][kg * 8];
            const f16x8 ub1 = *(const f16x8*)&PU[col][32 + kg * 8];
#pragma unroll
            for (int mt = 0; mt < 4; ++mt) {
                f32x4 ac = {0.f, 0.f, 0.f, 0.f};
                ac = __builtin_amdgcn_mfma_f32_16x16x32_f16(Tf[mt][0], xbA[nt], ac, 0,0,0);
                ac = __builtin_amdgcn_mfma_f32_16x16x32_f16(Tf[mt][1], xbB[nt], ac, 0,0,0);
                ac = __builtin_amdgcn_mfma_f32_16x16x32_f16(Mf[mt][0], ub0, ac, 0,0,0);
                ac = __builtin_amdgcn_mfma_f32_16x16x32_f16(Mf[mt][1], ub1, ac, 0,0,0);
                const int t0 = mt * 16 + kg * 4;
                const f16x4 xs = *(const f16x4*)&Xl[col][t0];
                f16x4 pk;
#pragma unroll
                for (int r = 0; r < 4; ++r) {
                    const float y  = fmaf(Dh, (float)xs[r], ac[r]);
                    const float y2 = y * y;
                    const float arg = y * fmaf(-0.10294502f, y2, -2.30218425f);
                    const float e   = __builtin_amdgcn_exp2f(arg);
                    pk[r] = (f16)(y * __builtin_amdgcn_rcpf(1.0f + e));
                }
                *(f16x4*)&yb[(size_t)cc * 64 + t0] = pk;
            }
        }
    }
}

extern "C" void kernel_launch(void* const* d_in, const int* in_sizes, int n_in,
                              void* d_out, int out_size, void* d_ws, size_t ws_size,
                              hipStream_t stream) {
    (void)in_sizes; (void)n_in; (void)out_size; (void)ws_size;
    const float* x    = (const float*)d_in[0];
    const float* ldt  = (const float*)d_in[1];
    const float* Arl  = (const float*)d_in[2];
    const float* Aim  = (const float*)d_in[3];
    const float* Bre  = (const float*)d_in[4];
    const float* Bim  = (const float*)d_in[5];
    const float* Cre  = (const float*)d_in[6];
    const float* Cim  = (const float*)d_in[7];
    const float* Dv   = (const float*)d_in[8];
    float* out = (float*)d_out;
    float* st_re = out + (size_t)B_ * L_ * H_;       // ys first
    float* st_im = st_re + (size_t)B_ * H_ * N2_;    // then imag plane

    // xT (H,B,L) f16 = 32 MiB lives in out's y region (y not written until
    // kernel C, which doesn't read xT). yT (32 MiB) lives in the workspace.
    f16* xT = (f16*)out;
    f16* yT = (f16*)d_ws;

    hipLaunchKernelGGL(k_trin, dim3(64 * 8 * B_), dim3(256), 0, stream, x, xT);
    hipLaunchKernelGGL(s4d_conv_kernel, dim3(1024), dim3(THREADS), 0, stream,
                       xT, ldt, Arl, Aim, Bre, Bim, Cre, Cim, Dv,
                       yT, st_re, st_im);
    hipLaunchKernelGGL(k_trout, dim3(64 * 8 * B_), dim3(256), 0, stream,
                       yT, out);
}

// Round 14
// 175.031 us; speedup vs baseline: 1.4218x; 1.4218x over previous
//
#include <hip/hip_runtime.h>
#include <math.h>

// S4D — round 20: r19 with the rule-#20 regression fixed.
// r19's conv 53->120us regression: xbA[4]/xbB[4] were runtime-indexed
// (P5/P7 were '#pragma unroll 1' loops) -> compiler lowered them to
// select-chains/scratch (VALUBusy 26->64%). Fix: FULLY UNROLL P5 and P7
// so all array indices are compile-time constants; registers are free
// (occupancy is LDS-capped at 2 blocks/CU = 2 waves/SIMD -> 256 VGPR).
// Keeps r19's wins: dApow[n][66] transposed table (bank conflicts
// 9.9M -> 1.18M, verified) and P7 reuse of P5's X fragments.

#define H_  512
#define L_  4096
#define B_  8
#define N2_ 32
#define NC  64            // chunks of 64 timesteps
#define THREADS 256
#define COLS 256          // columns per conv block = 4 b x 64 c
#define RSTR 72           // padded LDS row stride, f16 units

typedef _Float16 f16;
typedef _Float16 f16x8 __attribute__((ext_vector_type(8)));
typedef _Float16 f16x4 __attribute__((ext_vector_type(4)));
typedef float    f32x4 __attribute__((ext_vector_type(4)));

__device__ __forceinline__ float bfly1(float v) {   // xor 1: quad_perm [1,0,3,2]
    return __int_as_float(__builtin_amdgcn_update_dpp(
        0, __float_as_int(v), 0xB1, 0xf, 0xf, true));
}

// ---------------- kernel A: x (B,L,H) f32 -> xT (H,B,L) f16 ----------------
__global__ __launch_bounds__(256) void k_trin(
    const float* __restrict__ x, f16* __restrict__ xT)
{
    __shared__ float tl[64][65];
    const int bid = (int)blockIdx.x;
    const int tt = bid & 63, hh = (bid >> 6) & 7, b = bid >> 9;
    const int t0 = tt * 64, h0 = hh * 64;
    const int tid = threadIdx.x;

    const float* src = x + ((size_t)b * L_ + t0) * H_ + h0;
#pragma unroll
    for (int i = 0; i < 4; ++i) {
        const int e = i * 256 + tid;
        const int t = e >> 4, hq = e & 15;          // load 4 consecutive h
        const f32x4 v = *(const f32x4*)&src[(size_t)t * H_ + hq * 4];
#pragma unroll
        for (int j = 0; j < 4; ++j) tl[hq * 4 + j][t] = v[j];
    }
    __syncthreads();
#pragma unroll
    for (int i = 0; i < 2; ++i) {
        const int e = i * 256 + tid;
        const int hI = e >> 3, tq = e & 7;          // store 8 consecutive t
        f16x8 pk;
#pragma unroll
        for (int j = 0; j < 8; ++j) pk[j] = (f16)tl[hI][tq * 8 + j];
        *(f16x8*)&xT[((size_t)(h0 + hI) * B_ + b) * L_ + t0 + tq * 8] = pk;
    }
}

// ---------------- kernel C: yT (H,B,L) f16 -> y (B,L,H) f32 ----------------
__global__ __launch_bounds__(256) void k_trout(
    const f16* __restrict__ yT, float* __restrict__ y)
{
    __shared__ float tl[64][65];
    const int bid = (int)blockIdx.x;
    const int tt = bid & 63, hh = (bid >> 6) & 7, b = bid >> 9;
    const int t0 = tt * 64, h0 = hh * 64;
    const int tid = threadIdx.x;

#pragma unroll
    for (int i = 0; i < 2; ++i) {
        const int e = i * 256 + tid;
        const int hI = e >> 3, tq = e & 7;          // load 8 consecutive t
        const f16x8 v = *(const f16x8*)
            &yT[((size_t)(h0 + hI) * B_ + b) * L_ + t0 + tq * 8];
#pragma unroll
        for (int j = 0; j < 8; ++j) tl[tq * 8 + j][hI] = (float)v[j];
    }
    __syncthreads();
    float* dst = y + ((size_t)b * L_ + t0) * H_ + h0;
#pragma unroll
    for (int i = 0; i < 4; ++i) {
        const int e = i * 256 + tid;
        const int t = e >> 4, hq = e & 15;          // store 4 consecutive h
        f32x4 v;
#pragma unroll
        for (int j = 0; j < 4; ++j) v[j] = tl[t][hq * 4 + j];
        *(f32x4*)&dst[(size_t)t * H_ + hq * 4] = v;
    }
}

// ---------------- kernel B: per-h chunked convolution ----------------------
__global__ __launch_bounds__(THREADS, 2) void s4d_conv_kernel(
    const f16*  __restrict__ xT,          // (H, B, L) f16
    const float* __restrict__ log_dt,     // (H,)
    const float* __restrict__ A_real_log, // (H, N2)
    const float* __restrict__ A_imag,     // (H, N2)
    const float* __restrict__ B_re,       // (H, N2)
    const float* __restrict__ B_im,       // (H, N2)
    const float* __restrict__ C_re,       // (H, N2)
    const float* __restrict__ C_im,       // (H, N2)
    const float* __restrict__ Dv,         // (H,)
    f16*  __restrict__ yT,                // (H, B, L) f16 (gelu'd)
    float* __restrict__ st_re,            // (B, H, N2)
    float* __restrict__ st_im)            // (B, H, N2)
{
    __shared__ f16 Xl[COLS][RSTR];                 // 36.9 KB
    __shared__ f16 PU[COLS][RSTR];                 // 36.9 KB
    __shared__ float s_xr[32], s_xi[32], s_dBr[32], s_dBi[32],
                     s_wr[32], s_wi[32], s_wdr[32], s_wdi[32],
                     s_Lr[32], s_Li[32], s_k[64];

    // XCD swizzle: XCD k owns h in [k*64, (k+1)*64), both b-halves.
    const int bid = (int)blockIdx.x;
    const int li  = bid >> 3;                       // 0..127
    const int h   = (bid & 7) * 64 + (li >> 1);
    const int bh  = li & 1;                         // batch half (b = bh*4+w)

    const int tid = threadIdx.x;
    const int l   = tid & 63;
    const int w   = tid >> 6;                       // wave = local batch

    // ---- P0: per-mode ZOH constants (32 threads) ----
    if (tid < 32) {
        const int n = tid, hn = h * N2_ + n;
        const float dt = expf(log_dt[h]);
        const float Ar = -expf(A_real_log[hn]);
        const float Ai = A_imag[hn];
        const float xr = dt * Ar, xi = dt * Ai;
        s_xr[n] = xr; s_xi[n] = xi;
        const float ex = expf(xr), cs = cosf(xi), sn = sinf(xi);
        const float sh  = sinf(0.5f * xi);
        const float emr = expm1f(xr) * cs - 2.0f * sh * sh;  // Re(expm1(dtA))
        const float emi = ex * sn;
        const float ia  = 1.0f / (Ar * Ar + Ai * Ai);
        const float tr  = (emr * Ar + emi * Ai) * ia;
        const float ti  = (emi * Ar - emr * Ai) * ia;
        const float Brv = B_re[hn], Biv = B_im[hn];
        const float dBr = Brv * tr - Biv * ti, dBi = Brv * ti + Biv * tr;
        s_dBr[n] = dBr; s_dBi[n] = dBi;
        const float wr = 2.0f * C_re[hn], wi = 2.0f * C_im[hn];
        s_wr[n] = wr; s_wi[n] = wi;
        s_wdr[n] = wr * dBr - wi * dBi;             // w*dB
        s_wdi[n] = wr * dBi + wi * dBr;
    }
    const float Dh = Dv[h];
    __syncthreads();

    // ---- P1: dApow[n][p] = dA_n^p, p = 0..64, transposed layout [n][66]
    // (stride 66 -> conflict-free build reads; r19-verified 9.9M -> 1.2M) ----
    float* pr = (float*)&PU[0][0];                  // [32][66]
    float* pi = pr + 32 * 66;
    for (int e = tid; e < 2048; e += THREADS) {     // p = 0..63
        const int n = e >> 6, p = e & 63;
        const float ex = expf((float)p * s_xr[n]);
        float sn, cs; sincosf((float)p * s_xi[n], &sn, &cs);
        pr[n * 66 + p] = ex * cs; pi[n * 66 + p] = ex * sn;
    }
    if (tid < 32) {                                 // p = 64
        const int n = tid;
        const float ex = expf(64.f * s_xr[n]);
        float sn, cs; sincosf(64.f * s_xi[n], &sn, &cs);
        pr[n * 66 + 64] = ex * cs; pi[n * 66 + 64] = ex * sn;
    }
    __syncthreads();

    // ---- P2: build k, Lambda, M, V (then T after barrier) ----
    if (tid < 64) {                                 // k[d] = Re(w dB dA^d)
        float acc = 0.f;
        for (int n = 0; n < 32; ++n)
            acc += s_wdr[n] * pr[n * 66 + tid] - s_wdi[n] * pi[n * 66 + tid];
        s_k[tid] = acc;
    }
    if (tid < 32) { s_Lr[tid] = pr[tid * 66 + 64]; s_Li[tid] = pi[tid * 66 + 64]; }
    for (int e = tid; e < 4096; e += THREADS) {     // M[t][j], rows 64..127
        const int t = e >> 6, j = e & 63, n = j >> 1;
        const float re = pr[n * 66 + t + 1], im = pi[n * 66 + t + 1];
        const float mv = (j & 1) ? -(s_wr[n] * im + s_wi[n] * re)
                                 :  (s_wr[n] * re - s_wi[n] * im);
        Xl[64 + t][j] = (f16)mv;
    }
    for (int e = tid; e < 4096; e += THREADS) {     // V[r][s], rows 128..191
        const int r = e >> 6, s = e & 63, n = r >> 1;
        const float re = pr[n * 66 + 63 - s], im = pi[n * 66 + 63 - s];
        const float vv = (r & 1) ? (s_dBr[n] * im + s_dBi[n] * re)
                                 : (s_dBr[n] * re - s_dBi[n] * im);
        Xl[128 + r][s] = (f16)vv;
    }
    __syncthreads();
    for (int e = tid; e < 4096; e += THREADS) {     // T[t][s], rows 0..63
        const int t = e >> 6, s = e & 63;
        Xl[t][s] = (f16)((s <= t) ? s_k[t - s] : 0.f);
    }
    __syncthreads();

    // ---- P3: A-fragments to registers (row = l&15, kgroup = l>>4) ----
    const int row16 = l & 15, kg = l >> 4;
    f16x8 Tf[4][2], Mf[4][2], Vf[4][2];
#pragma unroll
    for (int mt = 0; mt < 4; ++mt)
#pragma unroll
        for (int ks = 0; ks < 2; ++ks) {
            const int off = ks * 32 + kg * 8;
            Tf[mt][ks] = *(const f16x8*)&Xl[      mt * 16 + row16][off];
            Mf[mt][ks] = *(const f16x8*)&Xl[ 64 + mt * 16 + row16][off];
            Vf[mt][ks] = *(const f16x8*)&Xl[128 + mt * 16 + row16][off];
        }
    __syncthreads();   // frags live in regs; Xl area free for X

    // ---- P4: load X — contiguous f16 reads from xT (thread = column) ----
    {
        const int col = tid, b = bh * 4 + (col >> 6), c = col & 63;
        const f16* xg = xT + ((size_t)h * B_ + b) * L_ + (size_t)c * 64;
#pragma unroll
        for (int s0 = 0; s0 < 64; s0 += 8)
            *(f16x8*)&Xl[col][s0] = *(const f16x8*)&xg[s0];
    }
    __syncthreads();

    const int colbase = w * 64;

    // ---- P5: P = V @ X; keep the X fragments live for P7.
    // FULLY UNROLLED: all xbA/xbB indices compile-time (rule #20) ----
    f16x8 xbA[4], xbB[4];
#pragma unroll
    for (int nt = 0; nt < 4; ++nt) {
        const int col = colbase + nt * 16 + row16;
        xbA[nt] = *(const f16x8*)&Xl[col][kg * 8];
        xbB[nt] = *(const f16x8*)&Xl[col][32 + kg * 8];
        f32x4 ac0 = {0.f,0.f,0.f,0.f}, ac1 = {0.f,0.f,0.f,0.f},
              ac2 = {0.f,0.f,0.f,0.f}, ac3 = {0.f,0.f,0.f,0.f};
        ac0 = __builtin_amdgcn_mfma_f32_16x16x32_f16(Vf[0][0], xbA[nt], ac0, 0,0,0);
        ac0 = __builtin_amdgcn_mfma_f32_16x16x32_f16(Vf[0][1], xbB[nt], ac0, 0,0,0);
        ac1 = __builtin_amdgcn_mfma_f32_16x16x32_f16(Vf[1][0], xbA[nt], ac1, 0,0,0);
        ac1 = __builtin_amdgcn_mfma_f32_16x16x32_f16(Vf[1][1], xbB[nt], ac1, 0,0,0);
        ac2 = __builtin_amdgcn_mfma_f32_16x16x32_f16(Vf[2][0], xbA[nt], ac2, 0,0,0);
        ac2 = __builtin_amdgcn_mfma_f32_16x16x32_f16(Vf[2][1], xbB[nt], ac2, 0,0,0);
        ac3 = __builtin_amdgcn_mfma_f32_16x16x32_f16(Vf[3][0], xbA[nt], ac3, 0,0,0);
        ac3 = __builtin_amdgcn_mfma_f32_16x16x32_f16(Vf[3][1], xbB[nt], ac3, 0,0,0);
        f32x4 a4[4] = {ac0, ac1, ac2, ac3};
#pragma unroll
        for (int mt = 0; mt < 4; ++mt) {
            f16x4 pv;
            pv[0] = (f16)a4[mt][0]; pv[1] = (f16)a4[mt][1];
            pv[2] = (f16)a4[mt][2]; pv[3] = (f16)a4[mt][3];
            *(f16x4*)&PU[col][mt * 16 + kg * 4] = pv;   // row j, col
        }
    }

    // ---- P6: wave-local diagonal recurrence over chunks (b = bh*4+w) ----
    {
        const int j = l, n = j >> 1;
        const float lr  = s_Lr[n];
        const float lis = (j & 1) ? s_Li[n] : -s_Li[n];
        float u = 0.f;
        for (int c = 0; c < NC; ++c) {
            const int col = colbase + c;
            const float pv = (float)PU[col][j];     // P_c component
            PU[col][j] = (f16)u;                    // store u_in(c) pre-update
            const float usw = bfly1(u);
            u = fmaf(lr, u, fmaf(lis, usw, pv));
        }
        const int pairIdx = (bh * 4 + w) * H_ + h;
        if ((j & 1) == 0) st_re[(size_t)pairIdx * N2_ + n] = u;
        else              st_im[(size_t)pairIdx * N2_ + n] = u;
    }

    // ---- P7: Y = T @ X + M @ U + D*x, gelu, contiguous f16 store to yT.
    // FULLY UNROLLED (rule #20) ----
    {
        const int b = bh * 4 + w;
        f16* yb = yT + ((size_t)h * B_ + b) * L_;
#pragma unroll
        for (int nt = 0; nt < 4; ++nt) {
            const int col = colbase + nt * 16 + row16;
            const int cc  = nt * 16 + row16;        // chunk index
            const f16x8 ub0 = *(const f16x8*)&PU[col][kg * 8];
            const f16x8 ub1 = *(const f16x8*)&PU[col][32 + kg * 8];
#pragma unroll
            for (int mt = 0; mt < 4; ++mt) {
                f32x4 ac = {0.f, 0.f, 0.f, 0.f};
                ac = __builtin_amdgcn_mfma_f32_16x16x32_f16(Tf[mt][0], xbA[nt], ac, 0,0,0);
                ac = __builtin_amdgcn_mfma_f32_16x16x32_f16(Tf[mt][1], xbB[nt], ac, 0,0,0);
                ac = __builtin_amdgcn_mfma_f32_16x16x32_f16(Mf[mt][0], ub0, ac, 0,0,0);
                ac = __builtin_amdgcn_mfma_f32_16x16x32_f16(Mf[mt][1], ub1, ac, 0,0,0);
                const int t0 = mt * 16 + kg * 4;
                const f16x4 xs = *(const f16x4*)&Xl[col][t0];
                f16x4 pk;
#pragma unroll
                for (int r = 0; r < 4; ++r) {
                    const float y  = fmaf(Dh, (float)xs[r], ac[r]);
                    const float y2 = y * y;
                    const float arg = y * fmaf(-0.10294502f, y2, -2.30218425f);
                    const float e   = __builtin_amdgcn_exp2f(arg);
                    pk[r] = (f16)(y * __builtin_amdgcn_rcpf(1.0f + e));
                }
                *(f16x4*)&yb[(size_t)cc * 64 + t0] = pk;
            }
        }
    }
}

extern "C" void kernel_launch(void* const* d_in, const int* in_sizes, int n_in,
                              void* d_out, int out_size, void* d_ws, size_t ws_size,
                              hipStream_t stream) {
    (void)in_sizes; (void)n_in; (void)out_size; (void)ws_size;
    const float* x    = (const float*)d_in[0];
    const float* ldt  = (const float*)d_in[1];
    const float* Arl  = (const float*)d_in[2];
    const float* Aim  = (const float*)d_in[3];
    const float* Bre  = (const float*)d_in[4];
    const float* Bim  = (const float*)d_in[5];
    const float* Cre  = (const float*)d_in[6];
    const float* Cim  = (const float*)d_in[7];
    const float* Dv   = (const float*)d_in[8];
    float* out = (float*)d_out;
    float* st_re = out + (size_t)B_ * L_ * H_;       // ys first
    float* st_im = st_re + (size_t)B_ * H_ * N2_;    // then imag plane

    // xT (H,B,L) f16 = 32 MiB lives in out's y region (y not written until
    // kernel C, which doesn't read xT). yT (32 MiB) lives in the workspace.
    f16* xT = (f16*)out;
    f16* yT = (f16*)d_ws;

    hipLaunchKernelGGL(k_trin, dim3(64 * 8 * B_), dim3(256), 0, stream, x, xT);
    hipLaunchKernelGGL(s4d_conv_kernel, dim3(1024), dim3(THREADS), 0, stream,
                       xT, ldt, Arl, Aim, Bre, Bim, Cre, Cim, Dv,
                       yT, st_re, st_im);
    hipLaunchKernelGGL(k_trout, dim3(64 * 8 * B_), dim3(256), 0, stream,
                       yT, out);
}

// Round 15
// 174.575 us; speedup vs baseline: 1.4255x; 1.0026x over previous
//
#include <hip/hip_runtime.h>
#include <math.h>

// S4D — round 21: r20 pipeline with the per-h matrix build HOISTED into a
// separate kernel D (k_build, 512 blocks = 1/h): T/M/V f16 (12.6 MB) + Λ
// f32 go to the out-buffer's spare region (out+32MB, consumed by conv
// before k_trout overwrites). Conv's build phase (2080 transcendentals +
// 3 LDS fills + extra barriers, previously duplicated across the two
// b-half blocks of each h) becomes a 24.6 KB coalesced LDS stage.
// P6's serial LDS recurrence reads batched 8-deep (static pv[8]) so the
// ~130cyc LDS latency pipelines instead of sitting on the u-chain.
// A (x->xT f16) and C (yT->y f32) transposes unchanged (BW-bound).

#define H_  512
#define L_  4096
#define B_  8
#define N2_ 32
#define NC  64            // chunks of 64 timesteps
#define THREADS 256
#define COLS 256          // columns per conv block = 4 b x 64 c
#define RSTR 72           // padded LDS row stride, f16 units

typedef _Float16 f16;
typedef _Float16 f16x8 __attribute__((ext_vector_type(8)));
typedef _Float16 f16x4 __attribute__((ext_vector_type(4)));
typedef float    f32x4 __attribute__((ext_vector_type(4)));

__device__ __forceinline__ float bfly1(float v) {   // xor 1: quad_perm [1,0,3,2]
    return __int_as_float(__builtin_amdgcn_update_dpp(
        0, __float_as_int(v), 0xB1, 0xf, 0xf, true));
}

// ---------------- kernel A: x (B,L,H) f32 -> xT (H,B,L) f16 ----------------
__global__ __launch_bounds__(256) void k_trin(
    const float* __restrict__ x, f16* __restrict__ xT)
{
    __shared__ float tl[64][65];
    const int bid = (int)blockIdx.x;
    const int tt = bid & 63, hh = (bid >> 6) & 7, b = bid >> 9;
    const int t0 = tt * 64, h0 = hh * 64;
    const int tid = threadIdx.x;

    const float* src = x + ((size_t)b * L_ + t0) * H_ + h0;
#pragma unroll
    for (int i = 0; i < 4; ++i) {
        const int e = i * 256 + tid;
        const int t = e >> 4, hq = e & 15;          // load 4 consecutive h
        const f32x4 v = *(const f32x4*)&src[(size_t)t * H_ + hq * 4];
#pragma unroll
        for (int j = 0; j < 4; ++j) tl[hq * 4 + j][t] = v[j];
    }
    __syncthreads();
#pragma unroll
    for (int i = 0; i < 2; ++i) {
        const int e = i * 256 + tid;
        const int hI = e >> 3, tq = e & 7;          // store 8 consecutive t
        f16x8 pk;
#pragma unroll
        for (int j = 0; j < 8; ++j) pk[j] = (f16)tl[hI][tq * 8 + j];
        *(f16x8*)&xT[((size_t)(h0 + hI) * B_ + b) * L_ + t0 + tq * 8] = pk;
    }
}

// ---------------- kernel C: yT (H,B,L) f16 -> y (B,L,H) f32 ----------------
__global__ __launch_bounds__(256) void k_trout(
    const f16* __restrict__ yT, float* __restrict__ y)
{
    __shared__ float tl[64][65];
    const int bid = (int)blockIdx.x;
    const int tt = bid & 63, hh = (bid >> 6) & 7, b = bid >> 9;
    const int t0 = tt * 64, h0 = hh * 64;
    const int tid = threadIdx.x;

#pragma unroll
    for (int i = 0; i < 2; ++i) {
        const int e = i * 256 + tid;
        const int hI = e >> 3, tq = e & 7;          // load 8 consecutive t
        const f16x8 v = *(const f16x8*)
            &yT[((size_t)(h0 + hI) * B_ + b) * L_ + t0 + tq * 8];
#pragma unroll
        for (int j = 0; j < 8; ++j) tl[tq * 8 + j][hI] = (float)v[j];
    }
    __syncthreads();
    float* dst = y + ((size_t)b * L_ + t0) * H_ + h0;
#pragma unroll
    for (int i = 0; i < 4; ++i) {
        const int e = i * 256 + tid;
        const int t = e >> 4, hq = e & 15;          // store 4 consecutive h
        f32x4 v;
#pragma unroll
        for (int j = 0; j < 4; ++j) v[j] = tl[t][hq * 4 + j];
        *(f32x4*)&dst[(size_t)t * H_ + hq * 4] = v;
    }
}

// ---------------- kernel D: per-h matrix build -----------------------------
// G[h][192][64] f16: T rows 0..63, M 64..127, V 128..191. Lg[h][64] f32:
// Λ re at [0:32), im at [32:64).
__global__ __launch_bounds__(256) void k_build(
    const float* __restrict__ log_dt,
    const float* __restrict__ A_real_log,
    const float* __restrict__ A_imag,
    const float* __restrict__ B_re,
    const float* __restrict__ B_im,
    const float* __restrict__ C_re,
    const float* __restrict__ C_im,
    f16*  __restrict__ G,
    float* __restrict__ Lg)
{
    __shared__ float pr[32 * 66], pi[32 * 66];     // dApow [n][66], p=0..64
    __shared__ float s_xr[32], s_xi[32], s_dBr[32], s_dBi[32],
                     s_wr[32], s_wi[32], s_wdr[32], s_wdi[32], s_k[64];
    const int h   = (int)blockIdx.x;
    const int tid = threadIdx.x;

    if (tid < 32) {
        const int n = tid, hn = h * N2_ + n;
        const float dt = expf(log_dt[h]);
        const float Ar = -expf(A_real_log[hn]);
        const float Ai = A_imag[hn];
        const float xr = dt * Ar, xi = dt * Ai;
        s_xr[n] = xr; s_xi[n] = xi;
        const float ex = expf(xr), cs = cosf(xi), sn = sinf(xi);
        const float sh  = sinf(0.5f * xi);
        const float emr = expm1f(xr) * cs - 2.0f * sh * sh;  // Re(expm1(dtA))
        const float emi = ex * sn;
        const float ia  = 1.0f / (Ar * Ar + Ai * Ai);
        const float tr  = (emr * Ar + emi * Ai) * ia;
        const float ti  = (emi * Ar - emr * Ai) * ia;
        const float Brv = B_re[hn], Biv = B_im[hn];
        const float dBr = Brv * tr - Biv * ti, dBi = Brv * ti + Biv * tr;
        s_dBr[n] = dBr; s_dBi[n] = dBi;
        const float wr = 2.0f * C_re[hn], wi = 2.0f * C_im[hn];
        s_wr[n] = wr; s_wi[n] = wi;
        s_wdr[n] = wr * dBr - wi * dBi;             // w*dB
        s_wdi[n] = wr * dBi + wi * dBr;
    }
    __syncthreads();

    for (int e = tid; e < 2048; e += 256) {         // p = 0..63
        const int n = e >> 6, p = e & 63;
        const float ex = expf((float)p * s_xr[n]);
        float sn, cs; sincosf((float)p * s_xi[n], &sn, &cs);
        pr[n * 66 + p] = ex * cs; pi[n * 66 + p] = ex * sn;
    }
    if (tid < 32) {                                 // p = 64
        const int n = tid;
        const float ex = expf(64.f * s_xr[n]);
        float sn, cs; sincosf(64.f * s_xi[n], &sn, &cs);
        pr[n * 66 + 64] = ex * cs; pi[n * 66 + 64] = ex * sn;
    }
    __syncthreads();

    if (tid < 64) {                                 // k[d] = Re(w dB dA^d)
        float acc = 0.f;
        for (int n = 0; n < 32; ++n)
            acc += s_wdr[n] * pr[n * 66 + tid] - s_wdi[n] * pi[n * 66 + tid];
        s_k[tid] = acc;
    }
    if (tid < 32) {                                 // Λ = dA^64
        Lg[h * 64 + tid]      = pr[tid * 66 + 64];
        Lg[h * 64 + 32 + tid] = pi[tid * 66 + 64];
    }
    f16* Gh = G + (size_t)h * 192 * 64;
    for (int e = tid; e < 4096; e += 256) {         // M rows 64..127
        const int t = e >> 6, j = e & 63, n = j >> 1;
        const float re = pr[n * 66 + t + 1], im = pi[n * 66 + t + 1];
        const float mv = (j & 1) ? -(s_wr[n] * im + s_wi[n] * re)
                                 :  (s_wr[n] * re - s_wi[n] * im);
        Gh[(size_t)(64 + t) * 64 + j] = (f16)mv;
    }
    for (int e = tid; e < 4096; e += 256) {         // V rows 128..191
        const int r = e >> 6, s = e & 63, n = r >> 1;
        const float re = pr[n * 66 + 63 - s], im = pi[n * 66 + 63 - s];
        const float vv = (r & 1) ? (s_dBr[n] * im + s_dBi[n] * re)
                                 : (s_dBr[n] * re - s_dBi[n] * im);
        Gh[(size_t)(128 + r) * 64 + s] = (f16)vv;
    }
    __syncthreads();                                // s_k ready for all
    for (int e = tid; e < 4096; e += 256) {         // T rows 0..63
        const int t = e >> 6, s = e & 63;
        Gh[(size_t)t * 64 + s] = (f16)((s <= t) ? s_k[t - s] : 0.f);
    }
}

// ---------------- kernel B: per-h chunked convolution ----------------------
__global__ __launch_bounds__(THREADS, 2) void s4d_conv_kernel(
    const f16*  __restrict__ xT,          // (H, B, L) f16
    const f16*  __restrict__ G,           // (H, 192, 64) f16: T/M/V
    const float* __restrict__ Lg,         // (H, 64) f32: Λ re|im
    const float* __restrict__ Dv,         // (H,)
    f16*  __restrict__ yT,                // (H, B, L) f16 (gelu'd)
    float* __restrict__ st_re,            // (B, H, N2)
    float* __restrict__ st_im)            // (B, H, N2)
{
    __shared__ f16 Xl[COLS][RSTR];                 // 36.9 KB
    __shared__ f16 PU[COLS][RSTR];                 // 36.9 KB
    __shared__ float s_Lr[32], s_Li[32];

    // XCD swizzle: XCD k owns h in [k*64, (k+1)*64), both b-halves.
    const int bid = (int)blockIdx.x;
    const int li  = bid >> 3;                       // 0..127
    const int h   = (bid & 7) * 64 + (li >> 1);
    const int bh  = li & 1;                         // batch half (b = bh*4+w)

    const int tid = threadIdx.x;
    const int l   = tid & 63;
    const int w   = tid >> 6;                       // wave = local batch

    const float Dh = Dv[h];

    // ---- stage matrices: 24.6 KB coalesced from G (built by kernel D) ----
    {
        const f16* Gh = G + (size_t)h * 192 * 64;
        for (int e = tid; e < 1536; e += THREADS) { // 192 rows x 8 segs
            const int row = e >> 3, seg = e & 7;
            *(f16x8*)&Xl[row][seg * 8] =
                *(const f16x8*)&Gh[(size_t)row * 64 + seg * 8];
        }
        if (tid < 32) {
            s_Lr[tid] = Lg[h * 64 + tid];
            s_Li[tid] = Lg[h * 64 + 32 + tid];
        }
    }
    __syncthreads();

    // ---- A-fragments to registers (row = l&15, kgroup = l>>4) ----
    const int row16 = l & 15, kg = l >> 4;
    f16x8 Tf[4][2], Mf[4][2], Vf[4][2];
#pragma unroll
    for (int mt = 0; mt < 4; ++mt)
#pragma unroll
        for (int ks = 0; ks < 2; ++ks) {
            const int off = ks * 32 + kg * 8;
            Tf[mt][ks] = *(const f16x8*)&Xl[      mt * 16 + row16][off];
            Mf[mt][ks] = *(const f16x8*)&Xl[ 64 + mt * 16 + row16][off];
            Vf[mt][ks] = *(const f16x8*)&Xl[128 + mt * 16 + row16][off];
        }
    __syncthreads();   // frags live in regs; Xl area free for X

    // ---- load X — contiguous f16 reads from xT (thread = column) ----
    {
        const int col = tid, b = bh * 4 + (col >> 6), c = col & 63;
        const f16* xg = xT + ((size_t)h * B_ + b) * L_ + (size_t)c * 64;
#pragma unroll
        for (int s0 = 0; s0 < 64; s0 += 8)
            *(f16x8*)&Xl[col][s0] = *(const f16x8*)&xg[s0];
    }
    __syncthreads();

    const int colbase = w * 64;

    // ---- P5: P = V @ X; keep the X fragments live for P7 (fully unrolled,
    // rule #20) ----
    f16x8 xbA[4], xbB[4];
#pragma unroll
    for (int nt = 0; nt < 4; ++nt) {
        const int col = colbase + nt * 16 + row16;
        xbA[nt] = *(const f16x8*)&Xl[col][kg * 8];
        xbB[nt] = *(const f16x8*)&Xl[col][32 + kg * 8];
        f32x4 ac0 = {0.f,0.f,0.f,0.f}, ac1 = {0.f,0.f,0.f,0.f},
              ac2 = {0.f,0.f,0.f,0.f}, ac3 = {0.f,0.f,0.f,0.f};
        ac0 = __builtin_amdgcn_mfma_f32_16x16x32_f16(Vf[0][0], xbA[nt], ac0, 0,0,0);
        ac0 = __builtin_amdgcn_mfma_f32_16x16x32_f16(Vf[0][1], xbB[nt], ac0, 0,0,0);
        ac1 = __builtin_amdgcn_mfma_f32_16x16x32_f16(Vf[1][0], xbA[nt], ac1, 0,0,0);
        ac1 = __builtin_amdgcn_mfma_f32_16x16x32_f16(Vf[1][1], xbB[nt], ac1, 0,0,0);
        ac2 = __builtin_amdgcn_mfma_f32_16x16x32_f16(Vf[2][0], xbA[nt], ac2, 0,0,0);
        ac2 = __builtin_amdgcn_mfma_f32_16x16x32_f16(Vf[2][1], xbB[nt], ac2, 0,0,0);
        ac3 = __builtin_amdgcn_mfma_f32_16x16x32_f16(Vf[3][0], xbA[nt], ac3, 0,0,0);
        ac3 = __builtin_amdgcn_mfma_f32_16x16x32_f16(Vf[3][1], xbB[nt], ac3, 0,0,0);
        f32x4 a4[4] = {ac0, ac1, ac2, ac3};
#pragma unroll
        for (int mt = 0; mt < 4; ++mt) {
            f16x4 pv;
            pv[0] = (f16)a4[mt][0]; pv[1] = (f16)a4[mt][1];
            pv[2] = (f16)a4[mt][2]; pv[3] = (f16)a4[mt][3];
            *(f16x4*)&PU[col][mt * 16 + kg * 4] = pv;   // row j, col
        }
    }

    // ---- P6: wave-local diagonal recurrence, LDS reads batched 8-deep ----
    {
        const int j = l, n = j >> 1;
        const float lr  = s_Lr[n];
        const float lis = (j & 1) ? s_Li[n] : -s_Li[n];
        float u = 0.f;
        for (int c0 = 0; c0 < NC; c0 += 8) {
            float pv[8];
#pragma unroll
            for (int k2 = 0; k2 < 8; ++k2)
                pv[k2] = (float)PU[colbase + c0 + k2][j];   // pipelined reads
#pragma unroll
            for (int k2 = 0; k2 < 8; ++k2) {
                PU[colbase + c0 + k2][j] = (f16)u;  // store u_in pre-update
                const float usw = bfly1(u);
                u = fmaf(lr, u, fmaf(lis, usw, pv[k2]));
            }
        }
        const int pairIdx = (bh * 4 + w) * H_ + h;
        if ((j & 1) == 0) st_re[(size_t)pairIdx * N2_ + n] = u;
        else              st_im[(size_t)pairIdx * N2_ + n] = u;
    }

    // ---- P7: Y = T @ X + M @ U + D*x, gelu, contiguous f16 store to yT ----
    {
        const int b = bh * 4 + w;
        f16* yb = yT + ((size_t)h * B_ + b) * L_;
#pragma unroll
        for (int nt = 0; nt < 4; ++nt) {
            const int col = colbase + nt * 16 + row16;
            const int cc  = nt * 16 + row16;        // chunk index
            const f16x8 ub0 = *(const f16x8*)&PU[col][kg * 8];
            const f16x8 ub1 = *(const f16x8*)&PU[col][32 + kg * 8];
#pragma unroll
            for (int mt = 0; mt < 4; ++mt) {
                f32x4 ac = {0.f, 0.f, 0.f, 0.f};
                ac = __builtin_amdgcn_mfma_f32_16x16x32_f16(Tf[mt][0], xbA[nt], ac, 0,0,0);
                ac = __builtin_amdgcn_mfma_f32_16x16x32_f16(Tf[mt][1], xbB[nt], ac, 0,0,0);
                ac = __builtin_amdgcn_mfma_f32_16x16x32_f16(Mf[mt][0], ub0, ac, 0,0,0);
                ac = __builtin_amdgcn_mfma_f32_16x16x32_f16(Mf[mt][1], ub1, ac, 0,0,0);
                const int t0 = mt * 16 + kg * 4;
                const f16x4 xs = *(const f16x4*)&Xl[col][t0];
                f16x4 pk;
#pragma unroll
                for (int r = 0; r < 4; ++r) {
                    const float y  = fmaf(Dh, (float)xs[r], ac[r]);
                    const float y2 = y * y;
                    const float arg = y * fmaf(-0.10294502f, y2, -2.30218425f);
                    const float e   = __builtin_amdgcn_exp2f(arg);
                    pk[r] = (f16)(y * __builtin_amdgcn_rcpf(1.0f + e));
                }
                *(f16x4*)&yb[(size_t)cc * 64 + t0] = pk;
            }
        }
    }
}

extern "C" void kernel_launch(void* const* d_in, const int* in_sizes, int n_in,
                              void* d_out, int out_size, void* d_ws, size_t ws_size,
                              hipStream_t stream) {
    (void)in_sizes; (void)n_in; (void)out_size; (void)ws_size;
    const float* x    = (const float*)d_in[0];
    const float* ldt  = (const float*)d_in[1];
    const float* Arl  = (const float*)d_in[2];
    const float* Aim  = (const float*)d_in[3];
    const float* Bre  = (const float*)d_in[4];
    const float* Bim  = (const float*)d_in[5];
    const float* Cre  = (const float*)d_in[6];
    const float* Cim  = (const float*)d_in[7];
    const float* Dv   = (const float*)d_in[8];
    float* out = (float*)d_out;
    float* st_re = out + (size_t)B_ * L_ * H_;       // ys first (64 MB)
    float* st_im = st_re + (size_t)B_ * H_ * N2_;    // then imag plane

    // Scratch layout inside the 64 MB y region (overwritten only by k_trout
    // at the very end): xT f16 32 MB at offset 0; G f16 12.6 MB at +32 MB;
    // Lg f32 131 KB after G. yT f16 32 MB lives in the workspace.
    f16*   xT = (f16*)out;
    f16*   G  = (f16*)((char*)out + 33554432);
    float* Lg = (float*)((char*)out + 33554432 + (size_t)H_ * 192 * 64 * 2);
    f16*   yT = (f16*)d_ws;

    hipLaunchKernelGGL(k_trin, dim3(64 * 8 * B_), dim3(256), 0, stream, x, xT);
    hipLaunchKernelGGL(k_build, dim3(H_), dim3(256), 0, stream,
                       ldt, Arl, Aim, Bre, Bim, Cre, Cim, G, Lg);
    hipLaunchKernelGGL(s4d_conv_kernel, dim3(1024), dim3(THREADS), 0, stream,
                       xT, G, Lg, Dv, yT, st_re, st_im);
    hipLaunchKernelGGL(k_trout, dim3(64 * 8 * B_), dim3(256), 0, stream,
                       yT, out);
}

// Round 16
// 172.829 us; speedup vs baseline: 1.4399x; 1.0101x over previous
//
#include <hip/hip_runtime.h>
#include <math.h>

// S4D — round 22: conv occupancy doubled via D-diagonal fold + LDS aliasing.
//  - y = T@X + M@U + D*x  ==  (T + D·I)@X + M@U : D folded into T's diagonal
//    in the build. P7 no longer reads X from LDS (fragments live in regs) ->
//    X is dead after P5 -> PU aliases Xl in ONE 37 KB buffer -> 4 blocks/CU
//    (was 2 at 75 KB) -> 4 waves/SIMD for a latency-bound kernel
//    (r20: VALUBusy 32%, MfmaUtil 5.4%, Occupancy 17%).
//    Aliasing safety: after the two staging barriers all LDS traffic is
//    wave-local (each wave touches only its own 64 cols; P5 writes depend on
//    its reads through MFMA, so in-wave order holds). One barrier dropped.
//  - k_build fused into k_trin's launch (blocks 4096..4607, union'd smem):
//    build hides under the transpose instead of serializing.

#define H_  512
#define L_  4096
#define B_  8
#define N2_ 32
#define NC  64            // chunks of 64 timesteps
#define THREADS 256
#define COLS 256          // columns per conv block = 4 b x 64 c
#define RSTR 72           // padded LDS row stride, f16 units

typedef _Float16 f16;
typedef _Float16 f16x8 __attribute__((ext_vector_type(8)));
typedef _Float16 f16x4 __attribute__((ext_vector_type(4)));
typedef float    f32x4 __attribute__((ext_vector_type(4)));

__device__ __forceinline__ float bfly1(float v) {   // xor 1: quad_perm [1,0,3,2]
    return __int_as_float(__builtin_amdgcn_update_dpp(
        0, __float_as_int(v), 0xB1, 0xf, 0xf, true));
}

// ------------- kernel PRE: blocks 0..4095 = x transpose, 4096.. = build ----
__global__ __launch_bounds__(256) void k_pre(
    const float* __restrict__ x,          // (B, L, H)
    f16*  __restrict__ xT,                // (H, B, L) f16
    const float* __restrict__ log_dt,
    const float* __restrict__ A_real_log,
    const float* __restrict__ A_imag,
    const float* __restrict__ B_re,
    const float* __restrict__ B_im,
    const float* __restrict__ C_re,
    const float* __restrict__ C_im,
    const float* __restrict__ Dv,
    f16*  __restrict__ G,                 // (H, 192, 64) f16: T' / M / V
    float* __restrict__ Lg)               // (H, 64) f32: Λ re|im
{
    __shared__ __align__(16) float smem[4608];      // 18.4 KB union
    const int bid = (int)blockIdx.x;
    const int tid = threadIdx.x;

    if (bid < 4096) {
        // ---- x (B,L,H) f32 -> xT (H,B,L) f16, 64x64 tile ----
        float (*tl)[65] = (float (*)[65])smem;
        const int tt = bid & 63, hh = (bid >> 6) & 7, b = bid >> 9;
        const int t0 = tt * 64, h0 = hh * 64;

        const float* src = x + ((size_t)b * L_ + t0) * H_ + h0;
#pragma unroll
        for (int i = 0; i < 4; ++i) {
            const int e = i * 256 + tid;
            const int t = e >> 4, hq = e & 15;
            const f32x4 v = *(const f32x4*)&src[(size_t)t * H_ + hq * 4];
#pragma unroll
            for (int j = 0; j < 4; ++j) tl[hq * 4 + j][t] = v[j];
        }
        __syncthreads();
#pragma unroll
        for (int i = 0; i < 2; ++i) {
            const int e = i * 256 + tid;
            const int hI = e >> 3, tq = e & 7;
            f16x8 pk;
#pragma unroll
            for (int j = 0; j < 8; ++j) pk[j] = (f16)tl[hI][tq * 8 + j];
            *(f16x8*)&xT[((size_t)(h0 + hI) * B_ + b) * L_ + t0 + tq * 8] = pk;
        }
        return;
    }

    // ---- per-h matrix build (h = bid - 4096) ----
    const int h = bid - 4096;
    float* pr = smem;                    // dApow re [n][66], p = 0..64
    float* pi = smem + 2112;             // dApow im
    float* sx = smem + 4224;             // constants block
    float* s_xr = sx;        float* s_xi = sx + 32;
    float* s_dBr = sx + 64;  float* s_dBi = sx + 96;
    float* s_wr = sx + 128;  float* s_wi = sx + 160;
    float* s_wdr = sx + 192; float* s_wdi = sx + 224;
    float* s_k = sx + 256;               // 64 entries

    if (tid < 32) {
        const int n = tid, hn = h * N2_ + n;
        const float dt = expf(log_dt[h]);
        const float Ar = -expf(A_real_log[hn]);
        const float Ai = A_imag[hn];
        const float xr = dt * Ar, xi = dt * Ai;
        s_xr[n] = xr; s_xi[n] = xi;
        const float ex = expf(xr), cs = cosf(xi), sn = sinf(xi);
        const float sh  = sinf(0.5f * xi);
        const float emr = expm1f(xr) * cs - 2.0f * sh * sh;  // Re(expm1(dtA))
        const float emi = ex * sn;
        const float ia  = 1.0f / (Ar * Ar + Ai * Ai);
        const float tr  = (emr * Ar + emi * Ai) * ia;
        const float ti  = (emi * Ar - emr * Ai) * ia;
        const float Brv = B_re[hn], Biv = B_im[hn];
        const float dBr = Brv * tr - Biv * ti, dBi = Brv * ti + Biv * tr;
        s_dBr[n] = dBr; s_dBi[n] = dBi;
        const float wr = 2.0f * C_re[hn], wi = 2.0f * C_im[hn];
        s_wr[n] = wr; s_wi[n] = wi;
        s_wdr[n] = wr * dBr - wi * dBi;             // w*dB
        s_wdi[n] = wr * dBi + wi * dBr;
    }
    __syncthreads();

    for (int e = tid; e < 2048; e += 256) {         // p = 0..63
        const int n = e >> 6, p = e & 63;
        const float ex = expf((float)p * s_xr[n]);
        float sn, cs; sincosf((float)p * s_xi[n], &sn, &cs);
        pr[n * 66 + p] = ex * cs; pi[n * 66 + p] = ex * sn;
    }
    if (tid < 32) {                                 // p = 64
        const int n = tid;
        const float ex = expf(64.f * s_xr[n]);
        float sn, cs; sincosf(64.f * s_xi[n], &sn, &cs);
        pr[n * 66 + 64] = ex * cs; pi[n * 66 + 64] = ex * sn;
    }
    __syncthreads();

    if (tid < 64) {                                 // k[d] = Re(w dB dA^d)
        float acc = 0.f;
        for (int n = 0; n < 32; ++n)
            acc += s_wdr[n] * pr[n * 66 + tid] - s_wdi[n] * pi[n * 66 + tid];
        s_k[tid] = acc;
    }
    if (tid < 32) {                                 // Λ = dA^64
        Lg[h * 64 + tid]      = pr[tid * 66 + 64];
        Lg[h * 64 + 32 + tid] = pi[tid * 66 + 64];
    }
    const float Dh = Dv[h];
    f16* Gh = G + (size_t)h * 192 * 64;
    for (int e = tid; e < 4096; e += 256) {         // M rows 64..127
        const int t = e >> 6, j = e & 63, n = j >> 1;
        const float re = pr[n * 66 + t + 1], im = pi[n * 66 + t + 1];
        const float mv = (j & 1) ? -(s_wr[n] * im + s_wi[n] * re)
                                 :  (s_wr[n] * re - s_wi[n] * im);
        Gh[(size_t)(64 + t) * 64 + j] = (f16)mv;
    }
    for (int e = tid; e < 4096; e += 256) {         // V rows 128..191
        const int r = e >> 6, s = e & 63, n = r >> 1;
        const float re = pr[n * 66 + 63 - s], im = pi[n * 66 + 63 - s];
        const float vv = (r & 1) ? (s_dBr[n] * im + s_dBi[n] * re)
                                 : (s_dBr[n] * re - s_dBi[n] * im);
        Gh[(size_t)(128 + r) * 64 + s] = (f16)vv;
    }
    __syncthreads();                                // s_k ready for all
    for (int e = tid; e < 4096; e += 256) {         // T' rows 0..63 (+D diag)
        const int t = e >> 6, s = e & 63;
        const float tv = (s <= t) ? (s_k[t - s] + (s == t ? Dh : 0.f)) : 0.f;
        Gh[(size_t)t * 64 + s] = (f16)tv;
    }
}

// ---------------- kernel C: yT (H,B,L) f16 -> y (B,L,H) f32 ----------------
__global__ __launch_bounds__(256) void k_trout(
    const f16* __restrict__ yT, float* __restrict__ y)
{
    __shared__ float tl[64][65];
    const int bid = (int)blockIdx.x;
    const int tt = bid & 63, hh = (bid >> 6) & 7, b = bid >> 9;
    const int t0 = tt * 64, h0 = hh * 64;
    const int tid = threadIdx.x;

#pragma unroll
    for (int i = 0; i < 2; ++i) {
        const int e = i * 256 + tid;
        const int hI = e >> 3, tq = e & 7;
        const f16x8 v = *(const f16x8*)
            &yT[((size_t)(h0 + hI) * B_ + b) * L_ + t0 + tq * 8];
#pragma unroll
        for (int j = 0; j < 8; ++j) tl[tq * 8 + j][hI] = (float)v[j];
    }
    __syncthreads();
    float* dst = y + ((size_t)b * L_ + t0) * H_ + h0;
#pragma unroll
    for (int i = 0; i < 4; ++i) {
        const int e = i * 256 + tid;
        const int t = e >> 4, hq = e & 15;
        f32x4 v;
#pragma unroll
        for (int j = 0; j < 4; ++j) v[j] = tl[t][hq * 4 + j];
        *(f32x4*)&dst[(size_t)t * H_ + hq * 4] = v;
    }
}

// ---------------- kernel B: per-h chunked convolution ----------------------
// ONE LDS buffer XP: phase 1 holds T'/M/V (rows 0..191); phase 2 holds X
// (all 256 cols); P5 overwrites each wave's own cols with P, then U.
__global__ __launch_bounds__(THREADS, 4) void s4d_conv_kernel(
    const f16*  __restrict__ xT,          // (H, B, L) f16
    const f16*  __restrict__ G,           // (H, 192, 64) f16: T'/M/V
    const float* __restrict__ Lg,         // (H, 64) f32: Λ re|im
    f16*  __restrict__ yT,                // (H, B, L) f16 (gelu'd)
    float* __restrict__ st_re,            // (B, H, N2)
    float* __restrict__ st_im)            // (B, H, N2)
{
    __shared__ f16 XP[COLS][RSTR];                 // 36.9 KB (single buffer)
    __shared__ float s_Lr[32], s_Li[32];

    // XCD swizzle: XCD k owns h in [k*64, (k+1)*64), both b-halves.
    const int bid = (int)blockIdx.x;
    const int li  = bid >> 3;                       // 0..127
    const int h   = (bid & 7) * 64 + (li >> 1);
    const int bh  = li & 1;                         // batch half (b = bh*4+w)

    const int tid = threadIdx.x;
    const int l   = tid & 63;
    const int w   = tid >> 6;                       // wave = local batch

    // ---- stage matrices: 24.6 KB coalesced from G ----
    {
        const f16* Gh = G + (size_t)h * 192 * 64;
        for (int e = tid; e < 1536; e += THREADS) { // 192 rows x 8 segs
            const int row = e >> 3, seg = e & 7;
            *(f16x8*)&XP[row][seg * 8] =
                *(const f16x8*)&Gh[(size_t)row * 64 + seg * 8];
        }
        if (tid < 32) {
            s_Lr[tid] = Lg[h * 64 + tid];
            s_Li[tid] = Lg[h * 64 + 32 + tid];
        }
    }
    __syncthreads();                                // barrier #1

    // ---- A-fragments to registers (row = l&15, kgroup = l>>4) ----
    const int row16 = l & 15, kg = l >> 4;
    f16x8 Tf[4][2], Mf[4][2], Vf[4][2];
#pragma unroll
    for (int mt = 0; mt < 4; ++mt)
#pragma unroll
        for (int ks = 0; ks < 2; ++ks) {
            const int off = ks * 32 + kg * 8;
            Tf[mt][ks] = *(const f16x8*)&XP[      mt * 16 + row16][off];
            Mf[mt][ks] = *(const f16x8*)&XP[ 64 + mt * 16 + row16][off];
            Vf[mt][ks] = *(const f16x8*)&XP[128 + mt * 16 + row16][off];
        }
    __syncthreads();                                // barrier #2 (frags safe)

    // ---- load X — contiguous f16 reads from xT (thread = column).
    // After this point ALL LDS traffic is wave-local (own 64 cols). ----
    {
        const int col = tid, b = bh * 4 + (col >> 6), c = col & 63;
        const f16* xg = xT + ((size_t)h * B_ + b) * L_ + (size_t)c * 64;
#pragma unroll
        for (int s0 = 0; s0 < 64; s0 += 8)
            *(f16x8*)&XP[col][s0] = *(const f16x8*)&xg[s0];
    }
    // no barrier: X cols are read only by the wave that wrote them

    const int colbase = w * 64;

    // ---- P5: P = V @ X; X fragments stay live for P7 (fully unrolled) ----
    f16x8 xbA[4], xbB[4];
#pragma unroll
    for (int nt = 0; nt < 4; ++nt) {
        const int col = colbase + nt * 16 + row16;
        xbA[nt] = *(const f16x8*)&XP[col][kg * 8];
        xbB[nt] = *(const f16x8*)&XP[col][32 + kg * 8];
        f32x4 ac0 = {0.f,0.f,0.f,0.f}, ac1 = {0.f,0.f,0.f,0.f},
              ac2 = {0.f,0.f,0.f,0.f}, ac3 = {0.f,0.f,0.f,0.f};
        ac0 = __builtin_amdgcn_mfma_f32_16x16x32_f16(Vf[0][0], xbA[nt], ac0, 0,0,0);
        ac0 = __builtin_amdgcn_mfma_f32_16x16x32_f16(Vf[0][1], xbB[nt], ac0, 0,0,0);
        ac1 = __builtin_amdgcn_mfma_f32_16x16x32_f16(Vf[1][0], xbA[nt], ac1, 0,0,0);
        ac1 = __builtin_amdgcn_mfma_f32_16x16x32_f16(Vf[1][1], xbB[nt], ac1, 0,0,0);
        ac2 = __builtin_amdgcn_mfma_f32_16x16x32_f16(Vf[2][0], xbA[nt], ac2, 0,0,0);
        ac2 = __builtin_amdgcn_mfma_f32_16x16x32_f16(Vf[2][1], xbB[nt], ac2, 0,0,0);
        ac3 = __builtin_amdgcn_mfma_f32_16x16x32_f16(Vf[3][0], xbA[nt], ac3, 0,0,0);
        ac3 = __builtin_amdgcn_mfma_f32_16x16x32_f16(Vf[3][1], xbB[nt], ac3, 0,0,0);
        f32x4 a4[4] = {ac0, ac1, ac2, ac3};
        // overwrite own cols with P (reads above already consumed; writes
        // are data-dependent on the reads through the MFMA chain)
#pragma unroll
        for (int mt = 0; mt < 4; ++mt) {
            f16x4 pv;
            pv[0] = (f16)a4[mt][0]; pv[1] = (f16)a4[mt][1];
            pv[2] = (f16)a4[mt][2]; pv[3] = (f16)a4[mt][3];
            *(f16x4*)&XP[col][mt * 16 + kg * 4] = pv;   // row j, col
        }
    }

    // ---- P6: wave-local diagonal recurrence, LDS reads batched 8-deep ----
    {
        const int j = l, n = j >> 1;
        const float lr  = s_Lr[n];
        const float lis = (j & 1) ? s_Li[n] : -s_Li[n];
        float u = 0.f;
        for (int c0 = 0; c0 < NC; c0 += 8) {
            float pv[8];
#pragma unroll
            for (int k2 = 0; k2 < 8; ++k2)
                pv[k2] = (float)XP[colbase + c0 + k2][j];   // pipelined reads
#pragma unroll
            for (int k2 = 0; k2 < 8; ++k2) {
                XP[colbase + c0 + k2][j] = (f16)u;  // store u_in pre-update
                const float usw = bfly1(u);
                u = fmaf(lr, u, fmaf(lis, usw, pv[k2]));
            }
        }
        const int pairIdx = (bh * 4 + w) * H_ + h;
        if ((j & 1) == 0) st_re[(size_t)pairIdx * N2_ + n] = u;
        else              st_im[(size_t)pairIdx * N2_ + n] = u;
    }

    // ---- P7: Y = T' @ X + M @ U, gelu, contiguous f16 store to yT ----
    {
        const int b = bh * 4 + w;
        f16* yb = yT + ((size_t)h * B_ + b) * L_;
#pragma unroll
        for (int nt = 0; nt < 4; ++nt) {
            const int col = colbase + nt * 16 + row16;
            const int cc  = nt * 16 + row16;        // chunk index
            const f16x8 ub0 = *(const f16x8*)&XP[col][kg * 8];
            const f16x8 ub1 = *(const f16x8*)&XP[col][32 + kg * 8];
#pragma unroll
            for (int mt = 0; mt < 4; ++mt) {
                f32x4 ac = {0.f, 0.f, 0.f, 0.f};
                ac = __builtin_amdgcn_mfma_f32_16x16x32_f16(Tf[mt][0], xbA[nt], ac, 0,0,0);
                ac = __builtin_amdgcn_mfma_f32_16x16x32_f16(Tf[mt][1], xbB[nt], ac, 0,0,0);
                ac = __builtin_amdgcn_mfma_f32_16x16x32_f16(Mf[mt][0], ub0, ac, 0,0,0);
                ac = __builtin_amdgcn_mfma_f32_16x16x32_f16(Mf[mt][1], ub1, ac, 0,0,0);
                const int t0 = mt * 16 + kg * 4;
                f16x4 pk;
#pragma unroll
                for (int r = 0; r < 4; ++r) {
                    const float y  = ac[r];         // D*x folded into T'
                    const float y2 = y * y;
                    const float arg = y * fmaf(-0.10294502f, y2, -2.30218425f);
                    const float e   = __builtin_amdgcn_exp2f(arg);
                    pk[r] = (f16)(y * __builtin_amdgcn_rcpf(1.0f + e));
                }
                *(f16x4*)&yb[(size_t)cc * 64 + t0] = pk;
            }
        }
    }
}

extern "C" void kernel_launch(void* const* d_in, const int* in_sizes, int n_in,
                              void* d_out, int out_size, void* d_ws, size_t ws_size,
                              hipStream_t stream) {
    (void)in_sizes; (void)n_in; (void)out_size; (void)ws_size;
    const float* x    = (const float*)d_in[0];
    const float* ldt  = (const float*)d_in[1];
    const float* Arl  = (const float*)d_in[2];
    const float* Aim  = (const float*)d_in[3];
    const float* Bre  = (const float*)d_in[4];
    const float* Bim  = (const float*)d_in[5];
    const float* Cre  = (const float*)d_in[6];
    const float* Cim  = (const float*)d_in[7];
    const float* Dv   = (const float*)d_in[8];
    float* out = (float*)d_out;
    float* st_re = out + (size_t)B_ * L_ * H_;       // ys first (64 MB)
    float* st_im = st_re + (size_t)B_ * H_ * N2_;    // then imag plane

    // Scratch inside the 64 MB y region (overwritten only by k_trout at the
    // end): xT f16 32 MB at 0; G f16 12.6 MB at +32 MB; Lg f32 after G.
    // yT f16 32 MB in the workspace.
    f16*   xT = (f16*)out;
    f16*   G  = (f16*)((char*)out + 33554432);
    float* Lg = (float*)((char*)out + 33554432 + (size_t)H_ * 192 * 64 * 2);
    f16*   yT = (f16*)d_ws;

    hipLaunchKernelGGL(k_pre, dim3(4096 + H_), dim3(256), 0, stream,
                       x, xT, ldt, Arl, Aim, Bre, Bim, Cre, Cim, Dv, G, Lg);
    hipLaunchKernelGGL(s4d_conv_kernel, dim3(1024), dim3(THREADS), 0, stream,
                       xT, G, Lg, yT, st_re, st_im);
    hipLaunchKernelGGL(k_trout, dim3(64 * 8 * B_), dim3(256), 0, stream,
                       yT, out);
}

// Round 17
// 162.311 us; speedup vs baseline: 1.5332x; 1.0648x over previous
//
#include <hip/hip_runtime.h>
#include <math.h>

// S4D — round 23: transpose-free pipeline. TWO kernels:
//   k_build: per-h T'(+D diag)/M/V f16 + Λ f32 into workspace (as r22).
//   conv-direct: 512 blocks = 64 h-groups x 8 b, 8 waves/block, wave w owns
//     h = hg*8+w with a PRIVATE LDS tile [64][72] f16. x is read directly
//     from (B,L,H) via cooperative 32B-granule loads (2 lanes/row x f32x4,
//     ~8 lines/VMEM-instr vs r16's catastrophic 64), converted f16, staged
//     into the 8 tiles; y is written back the same way. Matrices are read
//     per-wave straight from G (L2-resident; XCD swizzle puts all 8
//     b-blocks of an h-group on one XCD). Vf preloaded; Tf/Mf streamed
//     per-mt in P7 to keep peak VGPR ~110 < 128 (LB 512,4; 2 blocks/CU,
//     4 waves/SIMD). Eliminates both transpose kernels (~52us) and 190MB
//     of HBM round-trips.

#define H_  512
#define L_  4096
#define B_  8
#define N2_ 32
#define NC  64            // chunks of 64 timesteps
#define RSTR 72           // padded tile row stride, f16 units

typedef _Float16 f16;
typedef _Float16 f16x8 __attribute__((ext_vector_type(8)));
typedef _Float16 f16x4 __attribute__((ext_vector_type(4)));
typedef _Float16 f16x2 __attribute__((ext_vector_type(2)));
typedef float    f32x4 __attribute__((ext_vector_type(4)));

__device__ __forceinline__ float bfly1(float v) {   // xor 1: quad_perm [1,0,3,2]
    return __int_as_float(__builtin_amdgcn_update_dpp(
        0, __float_as_int(v), 0xB1, 0xf, 0xf, true));
}

// ---------------- kernel D: per-h matrix build (r22, verified) -------------
// G[h][192][64] f16: T'(+D diag) rows 0..63, M 64..127, V 128..191.
// Lg[h][64] f32: Λ re [0:32), im [32:64).
__global__ __launch_bounds__(256) void k_build(
    const float* __restrict__ log_dt,
    const float* __restrict__ A_real_log,
    const float* __restrict__ A_imag,
    const float* __restrict__ B_re,
    const float* __restrict__ B_im,
    const float* __restrict__ C_re,
    const float* __restrict__ C_im,
    const float* __restrict__ Dv,
    f16*  __restrict__ G,
    float* __restrict__ Lg)
{
    __shared__ float pr[32 * 66], pi[32 * 66];     // dApow [n][66], p=0..64
    __shared__ float s_xr[32], s_xi[32], s_dBr[32], s_dBi[32],
                     s_wr[32], s_wi[32], s_wdr[32], s_wdi[32], s_k[64];
    const int h   = (int)blockIdx.x;
    const int tid = threadIdx.x;

    if (tid < 32) {
        const int n = tid, hn = h * N2_ + n;
        const float dt = expf(log_dt[h]);
        const float Ar = -expf(A_real_log[hn]);
        const float Ai = A_imag[hn];
        const float xr = dt * Ar, xi = dt * Ai;
        s_xr[n] = xr; s_xi[n] = xi;
        const float ex = expf(xr), cs = cosf(xi), sn = sinf(xi);
        const float sh  = sinf(0.5f * xi);
        const float emr = expm1f(xr) * cs - 2.0f * sh * sh;  // Re(expm1(dtA))
        const float emi = ex * sn;
        const float ia  = 1.0f / (Ar * Ar + Ai * Ai);
        const float tr  = (emr * Ar + emi * Ai) * ia;
        const float ti  = (emi * Ar - emr * Ai) * ia;
        const float Brv = B_re[hn], Biv = B_im[hn];
        const float dBr = Brv * tr - Biv * ti, dBi = Brv * ti + Biv * tr;
        s_dBr[n] = dBr; s_dBi[n] = dBi;
        const float wr = 2.0f * C_re[hn], wi = 2.0f * C_im[hn];
        s_wr[n] = wr; s_wi[n] = wi;
        s_wdr[n] = wr * dBr - wi * dBi;             // w*dB
        s_wdi[n] = wr * dBi + wi * dBr;
    }
    __syncthreads();

    for (int e = tid; e < 2048; e += 256) {         // p = 0..63
        const int n = e >> 6, p = e & 63;
        const float ex = expf((float)p * s_xr[n]);
        float sn, cs; sincosf((float)p * s_xi[n], &sn, &cs);
        pr[n * 66 + p] = ex * cs; pi[n * 66 + p] = ex * sn;
    }
    if (tid < 32) {                                 // p = 64
        const int n = tid;
        const float ex = expf(64.f * s_xr[n]);
        float sn, cs; sincosf(64.f * s_xi[n], &sn, &cs);
        pr[n * 66 + 64] = ex * cs; pi[n * 66 + 64] = ex * sn;
    }
    __syncthreads();

    if (tid < 64) {                                 // k[d] = Re(w dB dA^d)
        float acc = 0.f;
        for (int n = 0; n < 32; ++n)
            acc += s_wdr[n] * pr[n * 66 + tid] - s_wdi[n] * pi[n * 66 + tid];
        s_k[tid] = acc;
    }
    if (tid < 32) {                                 // Λ = dA^64
        Lg[h * 64 + tid]      = pr[tid * 66 + 64];
        Lg[h * 64 + 32 + tid] = pi[tid * 66 + 64];
    }
    const float Dh = Dv[h];
    f16* Gh = G + (size_t)h * 192 * 64;
    for (int e = tid; e < 4096; e += 256) {         // M rows 64..127
        const int t = e >> 6, j = e & 63, n = j >> 1;
        const float re = pr[n * 66 + t + 1], im = pi[n * 66 + t + 1];
        const float mv = (j & 1) ? -(s_wr[n] * im + s_wi[n] * re)
                                 :  (s_wr[n] * re - s_wi[n] * im);
        Gh[(size_t)(64 + t) * 64 + j] = (f16)mv;
    }
    for (int e = tid; e < 4096; e += 256) {         // V rows 128..191
        const int r = e >> 6, s = e & 63, n = r >> 1;
        const float re = pr[n * 66 + 63 - s], im = pi[n * 66 + 63 - s];
        const float vv = (r & 1) ? (s_dBr[n] * im + s_dBi[n] * re)
                                 : (s_dBr[n] * re - s_dBi[n] * im);
        Gh[(size_t)(128 + r) * 64 + s] = (f16)vv;
    }
    __syncthreads();                                // s_k ready for all
    for (int e = tid; e < 4096; e += 256) {         // T' rows 0..63 (+D diag)
        const int t = e >> 6, s = e & 63;
        const float tv = (s <= t) ? (s_k[t - s] + (s == t ? Dh : 0.f)) : 0.f;
        Gh[(size_t)t * 64 + s] = (f16)tv;
    }
}

// ---------------- kernel B: direct-IO chunked convolution ------------------
__global__ __launch_bounds__(512, 4) void s4d_conv_kernel(
    const float* __restrict__ x,          // (B, L, H) f32
    const f16*  __restrict__ G,           // (H, 192, 64) f16: T'/M/V
    const float* __restrict__ Lg,         // (H, 64) f32: Λ re|im
    float* __restrict__ y,                // (B, L, H) f32 (gelu'd)
    float* __restrict__ st_re,            // (B, H, N2)
    float* __restrict__ st_im)            // (B, H, N2)
{
    __shared__ f16 XT[8][64][RSTR];                // 73,728 B: 8 wave tiles

    // XCD swizzle: XCD k owns lb in [64k,64k+64) = h-groups [8k,8k+8), all b.
    const int bid = (int)blockIdx.x;
    const int lb  = (bid & 7) * 64 + (bid >> 3);
    const int hg  = lb >> 3;                       // 0..63
    const int b   = lb & 7;

    const int tid = threadIdx.x;
    const int l   = tid & 63;
    const int w   = tid >> 6;                      // wave -> h = hg*8 + w
    const int h   = hg * 8 + w;
    const int row16 = l & 15, kg = l >> 4;

    const f16* Gh = G + (size_t)h * 192 * 64;

    // ---- Vf preload (global, L2-resident) + Λ ----
    f16x8 Vf[4][2];
#pragma unroll
    for (int mt = 0; mt < 4; ++mt)
#pragma unroll
        for (int ks = 0; ks < 2; ++ks)
            Vf[mt][ks] = *(const f16x8*)
                &Gh[(size_t)(128 + mt * 16 + row16) * 64 + ks * 32 + kg * 8];
    const float lr  = Lg[h * 64 + (l >> 1)];
    const float li0 = Lg[h * 64 + 32 + (l >> 1)];
    const float lis = (l & 1) ? li0 : -li0;

    // ---- cooperative X staging: 2 lanes/row x f32x4 (32B granule/row) ----
    const int h_off = (tid & 1) * 4;               // 0 or 4
    const int tp    = tid >> 1;                    // 0..255
    const float* xb_ = x + (size_t)b * L_ * H_ + hg * 8;
#pragma unroll 2
    for (int iter = 0; iter < 8; ++iter) {
        const int t0 = iter * 512 + tp * 2;        // even row, pair (t0,t0+1)
        const f32x4 v0 = *(const f32x4*)&xb_[(size_t)t0 * H_ + h_off];
        const f32x4 v1 = *(const f32x4*)&xb_[(size_t)(t0 + 1) * H_ + h_off];
        const int c = t0 >> 6, s0 = t0 & 63;
#pragma unroll
        for (int j = 0; j < 4; ++j) {
            f16x2 p; p[0] = (f16)v0[j]; p[1] = (f16)v1[j];
            *(f16x2*)&XT[h_off + j][c][s0] = p;
        }
    }
    __syncthreads();                               // barrier #1: X staged

    f16 (*Xw)[RSTR] = XT[w];                       // this wave's tile

    // ---- P5: P = V @ X; X fragments stay live for P7 (fully unrolled) ----
    f16x8 xbA[4], xbB[4];
#pragma unroll
    for (int nt = 0; nt < 4; ++nt) {
        const int col = nt * 16 + row16;
        xbA[nt] = *(const f16x8*)&Xw[col][kg * 8];
        xbB[nt] = *(const f16x8*)&Xw[col][32 + kg * 8];
        f32x4 ac0 = {0.f,0.f,0.f,0.f}, ac1 = {0.f,0.f,0.f,0.f},
              ac2 = {0.f,0.f,0.f,0.f}, ac3 = {0.f,0.f,0.f,0.f};
        ac0 = __builtin_amdgcn_mfma_f32_16x16x32_f16(Vf[0][0], xbA[nt], ac0, 0,0,0);
        ac0 = __builtin_amdgcn_mfma_f32_16x16x32_f16(Vf[0][1], xbB[nt], ac0, 0,0,0);
        ac1 = __builtin_amdgcn_mfma_f32_16x16x32_f16(Vf[1][0], xbA[nt], ac1, 0,0,0);
        ac1 = __builtin_amdgcn_mfma_f32_16x16x32_f16(Vf[1][1], xbB[nt], ac1, 0,0,0);
        ac2 = __builtin_amdgcn_mfma_f32_16x16x32_f16(Vf[2][0], xbA[nt], ac2, 0,0,0);
        ac2 = __builtin_amdgcn_mfma_f32_16x16x32_f16(Vf[2][1], xbB[nt], ac2, 0,0,0);
        ac3 = __builtin_amdgcn_mfma_f32_16x16x32_f16(Vf[3][0], xbA[nt], ac3, 0,0,0);
        ac3 = __builtin_amdgcn_mfma_f32_16x16x32_f16(Vf[3][1], xbB[nt], ac3, 0,0,0);
        const f32x4 a4[4] = {ac0, ac1, ac2, ac3};
#pragma unroll
        for (int mt = 0; mt < 4; ++mt) {
            f16x4 pv;
            pv[0] = (f16)a4[mt][0]; pv[1] = (f16)a4[mt][1];
            pv[2] = (f16)a4[mt][2]; pv[3] = (f16)a4[mt][3];
            *(f16x4*)&Xw[col][mt * 16 + kg * 4] = pv;   // P at row j, col
        }
    }

    // ---- P6: wave-local diagonal recurrence, LDS reads batched 8-deep ----
    {
        const int j = l, n = j >> 1;
        float u = 0.f;
        for (int c0 = 0; c0 < NC; c0 += 8) {
            float pv[8];
#pragma unroll
            for (int k2 = 0; k2 < 8; ++k2)
                pv[k2] = (float)Xw[c0 + k2][j];
#pragma unroll
            for (int k2 = 0; k2 < 8; ++k2) {
                Xw[c0 + k2][j] = (f16)u;           // store u_in pre-update
                const float usw = bfly1(u);
                u = fmaf(lr, u, fmaf(lis, usw, pv[k2]));
            }
        }
        const int pairIdx = b * H_ + h;
        if ((j & 1) == 0) st_re[(size_t)pairIdx * N2_ + n] = u;
        else              st_im[(size_t)pairIdx * N2_ + n] = u;
    }

    // ---- P7: Y = T' @ X + M @ U, gelu -> LDS tile (Tf/Mf streamed/mt) ----
    {
        f16x8 ub0[4], ub1[4];
#pragma unroll
        for (int nt = 0; nt < 4; ++nt) {           // read ALL U before y-writes
            const int col = nt * 16 + row16;
            ub0[nt] = *(const f16x8*)&Xw[col][kg * 8];
            ub1[nt] = *(const f16x8*)&Xw[col][32 + kg * 8];
        }
#pragma unroll
        for (int mt = 0; mt < 4; ++mt) {
            const size_t rT = (size_t)(mt * 16 + row16) * 64;
            const size_t rM = (size_t)(64 + mt * 16 + row16) * 64;
            const f16x8 Tf0 = *(const f16x8*)&Gh[rT + kg * 8];
            const f16x8 Tf1 = *(const f16x8*)&Gh[rT + 32 + kg * 8];
            const f16x8 Mf0 = *(const f16x8*)&Gh[rM + kg * 8];
            const f16x8 Mf1 = *(const f16x8*)&Gh[rM + 32 + kg * 8];
#pragma unroll
            for (int nt = 0; nt < 4; ++nt) {
                const int col = nt * 16 + row16;
                f32x4 ac = {0.f, 0.f, 0.f, 0.f};
                ac = __builtin_amdgcn_mfma_f32_16x16x32_f16(Tf0, xbA[nt], ac, 0,0,0);
                ac = __builtin_amdgcn_mfma_f32_16x16x32_f16(Tf1, xbB[nt], ac, 0,0,0);
                ac = __builtin_amdgcn_mfma_f32_16x16x32_f16(Mf0, ub0[nt], ac, 0,0,0);
                ac = __builtin_amdgcn_mfma_f32_16x16x32_f16(Mf1, ub1[nt], ac, 0,0,0);
                const int t0 = mt * 16 + kg * 4;
                f16x4 pk;
#pragma unroll
                for (int r = 0; r < 4; ++r) {
                    const float yv = ac[r];        // D*x folded into T'
                    const float y2 = yv * yv;
                    const float arg = yv * fmaf(-0.10294502f, y2, -2.30218425f);
                    const float e   = __builtin_amdgcn_exp2f(arg);
                    pk[r] = (f16)(yv * __builtin_amdgcn_rcpf(1.0f + e));
                }
                *(f16x4*)&Xw[col][t0] = pk;        // y at [chunk][t_in]
            }
        }
    }
    __syncthreads();                               // barrier #2: Y in tiles

    // ---- cooperative Y store: mirror of the X staging pattern ----
    {
        float* yb_ = y + (size_t)b * L_ * H_ + hg * 8;
#pragma unroll 2
        for (int iter = 0; iter < 8; ++iter) {
            const int t0 = iter * 512 + tp * 2;
            const int c = t0 >> 6, s0 = t0 & 63;
            f32x4 v0, v1;
#pragma unroll
            for (int j = 0; j < 4; ++j) {
                const f16x2 p = *(const f16x2*)&XT[h_off + j][c][s0];
                v0[j] = (float)p[0]; v1[j] = (float)p[1];
            }
            *(f32x4*)&yb_[(size_t)t0 * H_ + h_off]       = v0;
            *(f32x4*)&yb_[(size_t)(t0 + 1) * H_ + h_off] = v1;
        }
    }
}

extern "C" void kernel_launch(void* const* d_in, const int* in_sizes, int n_in,
                              void* d_out, int out_size, void* d_ws, size_t ws_size,
                              hipStream_t stream) {
    (void)in_sizes; (void)n_in; (void)out_size; (void)ws_size;
    const float* x    = (const float*)d_in[0];
    const float* ldt  = (const float*)d_in[1];
    const float* Arl  = (const float*)d_in[2];
    const float* Aim  = (const float*)d_in[3];
    const float* Bre  = (const float*)d_in[4];
    const float* Bim  = (const float*)d_in[5];
    const float* Cre  = (const float*)d_in[6];
    const float* Cim  = (const float*)d_in[7];
    const float* Dv   = (const float*)d_in[8];
    float* out = (float*)d_out;
    float* st_re = out + (size_t)B_ * L_ * H_;       // ys first (64 MB)
    float* st_im = st_re + (size_t)B_ * H_ * N2_;    // then imag plane

    // G f16 (12.6 MB) + Lg f32 (131 KB) live in the workspace.
    f16*   G  = (f16*)d_ws;
    float* Lg = (float*)((char*)d_ws + (size_t)H_ * 192 * 64 * 2);

    hipLaunchKernelGGL(k_build, dim3(H_), dim3(256), 0, stream,
                       ldt, Arl, Aim, Bre, Bim, Cre, Cim, Dv, G, Lg);
    hipLaunchKernelGGL(s4d_conv_kernel, dim3(512), dim3(512), 0, stream,
                       x, G, Lg, out, st_re, st_im);
}

// Round 18
// 153.610 us; speedup vs baseline: 1.6201x; 1.0566x over previous
//
#include <hip/hip_runtime.h>
#include <math.h>

// S4D — round 24: full-line direct IO. Blocks widened to 16 h (= one 64B
// line of x/y): grid 256 = 32 h-groups x 8 b, 1024 thr = 16 waves, one
// wave per h with a private LDS tile. Staging: 4 lanes x f32x4 = one FULL
// 64B line; 16 lines/instr (r23's 32B granule fragmented lines -> TA-bound,
// WRITE_SIZE showed 15-30% partial-line amplification). Tiles at stride
// 64*72+16 f16 (9248B: 16B-aligned, +16 pad rotates banks by 8/slot) with
// slot perm PHYS(h)=((h&3)<<2)|(h>>2) -> staging write instrs hit 4 tiles
// at rotations {0,8,16,24} = conflict-free. 144.5 KB LDS -> 1 block/CU,
// 16 waves (4/SIMD). Compute phases (P5/P6/P7) identical to r23 per wave.

#define H_  512
#define L_  4096
#define B_  8
#define N2_ 32
#define NC  64            // chunks of 64 timesteps
#define RSTR 72           // tile inner row stride, f16 units (144 B)
#define TSTR 4624         // f16 per tile slot: 64*72 + 16 pad (9248 B)

typedef _Float16 f16;
typedef _Float16 f16x8 __attribute__((ext_vector_type(8)));
typedef _Float16 f16x4 __attribute__((ext_vector_type(4)));
typedef _Float16 f16x2 __attribute__((ext_vector_type(2)));
typedef float    f32x4 __attribute__((ext_vector_type(4)));

__device__ __forceinline__ float bfly1(float v) {   // xor 1: quad_perm [1,0,3,2]
    return __int_as_float(__builtin_amdgcn_update_dpp(
        0, __float_as_int(v), 0xB1, 0xf, 0xf, true));
}

// ---------------- kernel D: per-h matrix build (r22/r23, verified) ---------
// G[h][192][64] f16: T'(+D diag) rows 0..63, M 64..127, V 128..191.
// Lg[h][64] f32: Λ re [0:32), im [32:64).
__global__ __launch_bounds__(256) void k_build(
    const float* __restrict__ log_dt,
    const float* __restrict__ A_real_log,
    const float* __restrict__ A_imag,
    const float* __restrict__ B_re,
    const float* __restrict__ B_im,
    const float* __restrict__ C_re,
    const float* __restrict__ C_im,
    const float* __restrict__ Dv,
    f16*  __restrict__ G,
    float* __restrict__ Lg)
{
    __shared__ float pr[32 * 66], pi[32 * 66];     // dApow [n][66], p=0..64
    __shared__ float s_xr[32], s_xi[32], s_dBr[32], s_dBi[32],
                     s_wr[32], s_wi[32], s_wdr[32], s_wdi[32], s_k[64];
    const int h   = (int)blockIdx.x;
    const int tid = threadIdx.x;

    if (tid < 32) {
        const int n = tid, hn = h * N2_ + n;
        const float dt = expf(log_dt[h]);
        const float Ar = -expf(A_real_log[hn]);
        const float Ai = A_imag[hn];
        const float xr = dt * Ar, xi = dt * Ai;
        s_xr[n] = xr; s_xi[n] = xi;
        const float ex = expf(xr), cs = cosf(xi), sn = sinf(xi);
        const float sh  = sinf(0.5f * xi);
        const float emr = expm1f(xr) * cs - 2.0f * sh * sh;  // Re(expm1(dtA))
        const float emi = ex * sn;
        const float ia  = 1.0f / (Ar * Ar + Ai * Ai);
        const float tr  = (emr * Ar + emi * Ai) * ia;
        const float ti  = (emi * Ar - emr * Ai) * ia;
        const float Brv = B_re[hn], Biv = B_im[hn];
        const float dBr = Brv * tr - Biv * ti, dBi = Brv * ti + Biv * tr;
        s_dBr[n] = dBr; s_dBi[n] = dBi;
        const float wr = 2.0f * C_re[hn], wi = 2.0f * C_im[hn];
        s_wr[n] = wr; s_wi[n] = wi;
        s_wdr[n] = wr * dBr - wi * dBi;             // w*dB
        s_wdi[n] = wr * dBi + wi * dBr;
    }
    __syncthreads();

    for (int e = tid; e < 2048; e += 256) {         // p = 0..63
        const int n = e >> 6, p = e & 63;
        const float ex = expf((float)p * s_xr[n]);
        float sn, cs; sincosf((float)p * s_xi[n], &sn, &cs);
        pr[n * 66 + p] = ex * cs; pi[n * 66 + p] = ex * sn;
    }
    if (tid < 32) {                                 // p = 64
        const int n = tid;
        const float ex = expf(64.f * s_xr[n]);
        float sn, cs; sincosf(64.f * s_xi[n], &sn, &cs);
        pr[n * 66 + 64] = ex * cs; pi[n * 66 + 64] = ex * sn;
    }
    __syncthreads();

    if (tid < 64) {                                 // k[d] = Re(w dB dA^d)
        float acc = 0.f;
        for (int n = 0; n < 32; ++n)
            acc += s_wdr[n] * pr[n * 66 + tid] - s_wdi[n] * pi[n * 66 + tid];
        s_k[tid] = acc;
    }
    if (tid < 32) {                                 // Λ = dA^64
        Lg[h * 64 + tid]      = pr[tid * 66 + 64];
        Lg[h * 64 + 32 + tid] = pi[tid * 66 + 64];
    }
    const float Dh = Dv[h];
    f16* Gh = G + (size_t)h * 192 * 64;
    for (int e = tid; e < 4096; e += 256) {         // M rows 64..127
        const int t = e >> 6, j = e & 63, n = j >> 1;
        const float re = pr[n * 66 + t + 1], im = pi[n * 66 + t + 1];
        const float mv = (j & 1) ? -(s_wr[n] * im + s_wi[n] * re)
                                 :  (s_wr[n] * re - s_wi[n] * im);
        Gh[(size_t)(64 + t) * 64 + j] = (f16)mv;
    }
    for (int e = tid; e < 4096; e += 256) {         // V rows 128..191
        const int r = e >> 6, s = e & 63, n = r >> 1;
        const float re = pr[n * 66 + 63 - s], im = pi[n * 66 + 63 - s];
        const float vv = (r & 1) ? (s_dBr[n] * im + s_dBi[n] * re)
                                 : (s_dBr[n] * re - s_dBi[n] * im);
        Gh[(size_t)(128 + r) * 64 + s] = (f16)vv;
    }
    __syncthreads();                                // s_k ready for all
    for (int e = tid; e < 4096; e += 256) {         // T' rows 0..63 (+D diag)
        const int t = e >> 6, s = e & 63;
        const float tv = (s <= t) ? (s_k[t - s] + (s == t ? Dh : 0.f)) : 0.f;
        Gh[(size_t)t * 64 + s] = (f16)tv;
    }
}

// ---------------- kernel B: full-line direct-IO chunked convolution --------
__global__ __launch_bounds__(1024, 4) void s4d_conv_kernel(
    const float* __restrict__ x,          // (B, L, H) f32
    const f16*  __restrict__ G,           // (H, 192, 64) f16: T'/M/V
    const float* __restrict__ Lg,         // (H, 64) f32: Λ re|im
    float* __restrict__ y,                // (B, L, H) f32 (gelu'd)
    float* __restrict__ st_re,            // (B, H, N2)
    float* __restrict__ st_im)            // (B, H, N2)
{
    __shared__ f16 XT[16 * TSTR];                  // 147,968 B: 16 wave tiles

    // XCD swizzle: XCD k owns h-groups [4k,4k+4), all b.
    const int bid = (int)blockIdx.x;               // 0..255
    const int lb  = (bid & 7) * 32 + (bid >> 3);
    const int hg  = lb >> 3;                       // 0..31 (16-h group)
    const int b   = lb & 7;

    const int tid = threadIdx.x;
    const int l   = tid & 63;
    const int w   = tid >> 6;                      // wave -> h = hg*16 + w
    const int h   = hg * 16 + w;
    const int row16 = l & 15, kg = l >> 4;

    const f16* Gh = G + (size_t)h * 192 * 64;

    // ---- Vf preload (global, L2-resident) + Λ ----
    f16x8 Vf[4][2];
#pragma unroll
    for (int mt = 0; mt < 4; ++mt)
#pragma unroll
        for (int ks = 0; ks < 2; ++ks)
            Vf[mt][ks] = *(const f16x8*)
                &Gh[(size_t)(128 + mt * 16 + row16) * 64 + ks * 32 + kg * 8];
    const float lr  = Lg[h * 64 + (l >> 1)];
    const float li0 = Lg[h * 64 + 32 + (l >> 1)];
    const float lis = (l & 1) ? li0 : -li0;

    // ---- cooperative X staging: lane-quad = one FULL 64B line ----
    // thread: hq = tid&3 (h sub-quad), tp = tid>>2 (t-pair index)
    const int hq = tid & 3;
    const int tp = tid >> 2;                       // 0..255
    const float* xb_ = x + (size_t)b * L_ * H_ + hg * 16 + hq * 4;
#pragma unroll 2
    for (int iter = 0; iter < 8; ++iter) {
        const int t0 = iter * 512 + tp * 2;        // even row, pair (t0,t0+1)
        const f32x4 v0 = *(const f32x4*)&xb_[(size_t)t0 * H_];
        const f32x4 v1 = *(const f32x4*)&xb_[(size_t)(t0 + 1) * H_];
        const int c = t0 >> 6, s0 = t0 & 63;
#pragma unroll
        for (int j = 0; j < 4; ++j) {              // h_local = hq*4+j
            f16x2 p; p[0] = (f16)v0[j]; p[1] = (f16)v1[j];
            // slot PHYS(hq*4+j) = (j<<2)|hq -> per-j instr hits 4 tiles at
            // bank rotations {0,8,16,24}: conflict-free
            *(f16x2*)&XT[((j << 2) | hq) * TSTR + c * RSTR + s0] = p;
        }
    }
    __syncthreads();                               // barrier #1: X staged

    f16* Xw = &XT[(((w & 3) << 2) | (w >> 2)) * TSTR];   // PHYS(w)

    // ---- P5: P = V @ X; X fragments stay live for P7 (fully unrolled) ----
    f16x8 xbA[4], xbB[4];
#pragma unroll
    for (int nt = 0; nt < 4; ++nt) {
        const int col = nt * 16 + row16;
        xbA[nt] = *(const f16x8*)&Xw[col * RSTR + kg * 8];
        xbB[nt] = *(const f16x8*)&Xw[col * RSTR + 32 + kg * 8];
        f32x4 ac0 = {0.f,0.f,0.f,0.f}, ac1 = {0.f,0.f,0.f,0.f},
              ac2 = {0.f,0.f,0.f,0.f}, ac3 = {0.f,0.f,0.f,0.f};
        ac0 = __builtin_amdgcn_mfma_f32_16x16x32_f16(Vf[0][0], xbA[nt], ac0, 0,0,0);
        ac0 = __builtin_amdgcn_mfma_f32_16x16x32_f16(Vf[0][1], xbB[nt], ac0, 0,0,0);
        ac1 = __builtin_amdgcn_mfma_f32_16x16x32_f16(Vf[1][0], xbA[nt], ac1, 0,0,0);
        ac1 = __builtin_amdgcn_mfma_f32_16x16x32_f16(Vf[1][1], xbB[nt], ac1, 0,0,0);
        ac2 = __builtin_amdgcn_mfma_f32_16x16x32_f16(Vf[2][0], xbA[nt], ac2, 0,0,0);
        ac2 = __builtin_amdgcn_mfma_f32_16x16x32_f16(Vf[2][1], xbB[nt], ac2, 0,0,0);
        ac3 = __builtin_amdgcn_mfma_f32_16x16x32_f16(Vf[3][0], xbA[nt], ac3, 0,0,0);
        ac3 = __builtin_amdgcn_mfma_f32_16x16x32_f16(Vf[3][1], xbB[nt], ac3, 0,0,0);
        const f32x4 a4[4] = {ac0, ac1, ac2, ac3};
#pragma unroll
        for (int mt = 0; mt < 4; ++mt) {
            f16x4 pv;
            pv[0] = (f16)a4[mt][0]; pv[1] = (f16)a4[mt][1];
            pv[2] = (f16)a4[mt][2]; pv[3] = (f16)a4[mt][3];
            *(f16x4*)&Xw[col * RSTR + mt * 16 + kg * 4] = pv;  // P row j, col
        }
    }

    // ---- P6: wave-local diagonal recurrence, LDS reads batched 8-deep ----
    {
        const int j = l, n = j >> 1;
        float u = 0.f;
        for (int c0 = 0; c0 < NC; c0 += 8) {
            float pv[8];
#pragma unroll
            for (int k2 = 0; k2 < 8; ++k2)
                pv[k2] = (float)Xw[(c0 + k2) * RSTR + j];
#pragma unroll
            for (int k2 = 0; k2 < 8; ++k2) {
                Xw[(c0 + k2) * RSTR + j] = (f16)u; // store u_in pre-update
                const float usw = bfly1(u);
                u = fmaf(lr, u, fmaf(lis, usw, pv[k2]));
            }
        }
        const int pairIdx = b * H_ + h;
        if ((j & 1) == 0) st_re[(size_t)pairIdx * N2_ + n] = u;
        else              st_im[(size_t)pairIdx * N2_ + n] = u;
    }

    // ---- P7: Y = T' @ X + M @ U, gelu -> LDS tile (Tf/Mf streamed/mt) ----
    {
        f16x8 ub0[4], ub1[4];
#pragma unroll
        for (int nt = 0; nt < 4; ++nt) {           // read ALL U before y-writes
            const int col = nt * 16 + row16;
            ub0[nt] = *(const f16x8*)&Xw[col * RSTR + kg * 8];
            ub1[nt] = *(const f16x8*)&Xw[col * RSTR + 32 + kg * 8];
        }
#pragma unroll
        for (int mt = 0; mt < 4; ++mt) {
            const size_t rT = (size_t)(mt * 16 + row16) * 64;
            const size_t rM = (size_t)(64 + mt * 16 + row16) * 64;
            const f16x8 Tf0 = *(const f16x8*)&Gh[rT + kg * 8];
            const f16x8 Tf1 = *(const f16x8*)&Gh[rT + 32 + kg * 8];
            const f16x8 Mf0 = *(const f16x8*)&Gh[rM + kg * 8];
            const f16x8 Mf1 = *(const f16x8*)&Gh[rM + 32 + kg * 8];
#pragma unroll
            for (int nt = 0; nt < 4; ++nt) {
                const int col = nt * 16 + row16;
                f32x4 ac = {0.f, 0.f, 0.f, 0.f};
                ac = __builtin_amdgcn_mfma_f32_16x16x32_f16(Tf0, xbA[nt], ac, 0,0,0);
                ac = __builtin_amdgcn_mfma_f32_16x16x32_f16(Tf1, xbB[nt], ac, 0,0,0);
                ac = __builtin_amdgcn_mfma_f32_16x16x32_f16(Mf0, ub0[nt], ac, 0,0,0);
                ac = __builtin_amdgcn_mfma_f32_16x16x32_f16(Mf1, ub1[nt], ac, 0,0,0);
                const int t0 = mt * 16 + kg * 4;
                f16x4 pk;
#pragma unroll
                for (int r = 0; r < 4; ++r) {
                    const float yv = ac[r];        // D*x folded into T'
                    const float y2 = yv * yv;
                    const float arg = yv * fmaf(-0.10294502f, y2, -2.30218425f);
                    const float e   = __builtin_amdgcn_exp2f(arg);
                    pk[r] = (f16)(yv * __builtin_amdgcn_rcpf(1.0f + e));
                }
                *(f16x4*)&Xw[col * RSTR + t0] = pk;   // y at [chunk][t_in]
            }
        }
    }
    __syncthreads();                               // barrier #2: Y in tiles

    // ---- cooperative Y store: mirror of staging (full 64B lines) ----
    {
        float* yb_ = y + (size_t)b * L_ * H_ + hg * 16 + hq * 4;
#pragma unroll 2
        for (int iter = 0; iter < 8; ++iter) {
            const int t0 = iter * 512 + tp * 2;
            const int c = t0 >> 6, s0 = t0 & 63;
            f32x4 v0, v1;
#pragma unroll
            for (int j = 0; j < 4; ++j) {
                const f16x2 p = *(const f16x2*)
                    &XT[((j << 2) | hq) * TSTR + c * RSTR + s0];
                v0[j] = (float)p[0]; v1[j] = (float)p[1];
            }
            *(f32x4*)&yb_[(size_t)t0 * H_]       = v0;
            *(f32x4*)&yb_[(size_t)(t0 + 1) * H_] = v1;
        }
    }
}

extern "C" void kernel_launch(void* const* d_in, const int* in_sizes, int n_in,
                              void* d_out, int out_size, void* d_ws, size_t ws_size,
                              hipStream_t stream) {
    (void)in_sizes; (void)n_in; (void)out_size; (void)ws_size;
    const float* x    = (const float*)d_in[0];
    const float* ldt  = (const float*)d_in[1];
    const float* Arl  = (const float*)d_in[2];
    const float* Aim  = (const float*)d_in[3];
    const float* Bre  = (const float*)d_in[4];
    const float* Bim  = (const float*)d_in[5];
    const float* Cre  = (const float*)d_in[6];
    const float* Cim  = (const float*)d_in[7];
    const float* Dv   = (const float*)d_in[8];
    float* out = (float*)d_out;
    float* st_re = out + (size_t)B_ * L_ * H_;       // ys first (64 MB)
    float* st_im = st_re + (size_t)B_ * H_ * N2_;    // then imag plane

    // G f16 (12.6 MB) + Lg f32 (131 KB) live in the workspace.
    f16*   G  = (f16*)d_ws;
    float* Lg = (float*)((char*)d_ws + (size_t)H_ * 192 * 64 * 2);

    hipLaunchKernelGGL(k_build, dim3(H_), dim3(256), 0, stream,
                       ldt, Arl, Aim, Bre, Bim, Cre, Cim, Dv, G, Lg);
    hipLaunchKernelGGL(s4d_conv_kernel, dim3(256), dim3(1024), 0, stream,
                       x, G, Lg, out, st_re, st_im);
}